// Round 1
// baseline (812.331 us; speedup 1.0000x reference)
//
#include <hip/hip_runtime.h>
#include <math.h>

#define NNODES 50000
#define NEDGES 800000
#define INC    300
#define NGRAPH 256

// ---------------- GEMM: C[M,N] = act(A[M,K] @ W[K,N] + bias) ----------------
#define BM 64
#define BN 64
#define BK 16

__global__ __launch_bounds__(256) void gemm_bias_act(
    const float* __restrict__ A, int lda, int M, int K,
    const float* __restrict__ W, int ldw,
    const float* __restrict__ bias,
    float* __restrict__ C, int ldc, int c0,
    int relu)
{
    __shared__ float As[BK][BM];
    __shared__ float Ws[BK][BN];
    const int bm = blockIdx.x * BM;
    const int bn = blockIdx.y * BN;
    const int tid = threadIdx.x;
    const int tx = tid & 15;    // col group (4 cols)
    const int ty = tid >> 4;    // row group (4 rows)
    float acc[4][4] = {};

    for (int k0 = 0; k0 < K; k0 += BK) {
        // A tile: BM x BK, stored transposed As[k][m]
        #pragma unroll
        for (int i = tid; i < BM * BK; i += 256) {
            int r = i >> 4, c = i & 15;
            int gr = bm + r, gk = k0 + c;
            As[c][r] = (gr < M && gk < K) ? A[(size_t)gr * lda + gk] : 0.f;
        }
        // W tile: BK x BN
        #pragma unroll
        for (int i = tid; i < BK * BN; i += 256) {
            int c = i >> 6, nn = i & 63;
            int gk = k0 + c;
            Ws[c][nn] = (gk < K) ? W[(size_t)gk * ldw + bn + nn] : 0.f;
        }
        __syncthreads();
        #pragma unroll
        for (int kk = 0; kk < BK; ++kk) {
            float4 a = *reinterpret_cast<const float4*>(&As[kk][ty * 4]);
            float4 w = *reinterpret_cast<const float4*>(&Ws[kk][tx * 4]);
            acc[0][0] += a.x * w.x; acc[0][1] += a.x * w.y; acc[0][2] += a.x * w.z; acc[0][3] += a.x * w.w;
            acc[1][0] += a.y * w.x; acc[1][1] += a.y * w.y; acc[1][2] += a.y * w.z; acc[1][3] += a.y * w.w;
            acc[2][0] += a.z * w.x; acc[2][1] += a.z * w.y; acc[2][2] += a.z * w.z; acc[2][3] += a.z * w.w;
            acc[3][0] += a.w * w.x; acc[3][1] += a.w * w.y; acc[3][2] += a.w * w.z; acc[3][3] += a.w * w.w;
        }
        __syncthreads();
    }

    #pragma unroll
    for (int i = 0; i < 4; ++i) {
        int row = bm + ty * 4 + i;
        if (row >= M) continue;
        #pragma unroll
        for (int j = 0; j < 4; ++j) {
            int col = bn + tx * 4 + j;
            float v = acc[i][j] + bias[col];
            if (relu) v = fmaxf(v, 0.f);
            C[(size_t)row * ldc + c0 + col] = v;
        }
    }
}

// ---------------- CSR build (group edges by dst) ----------------
__global__ void k_hist(const int* __restrict__ dstv, int* __restrict__ deg, int E) {
    int e = blockIdx.x * 256 + threadIdx.x;
    if (e < E) atomicAdd(&deg[dstv[e]], 1);
}

__global__ void k_scan1(const int* __restrict__ deg, int* __restrict__ ex,
                        int* __restrict__ bsum, int n) {
    __shared__ int tmp[256];
    int i = blockIdx.x * 256 + threadIdx.x;
    int v = (i < n) ? deg[i] : 0;
    tmp[threadIdx.x] = v;
    __syncthreads();
    for (int off = 1; off < 256; off <<= 1) {
        int t = (threadIdx.x >= off) ? tmp[threadIdx.x - off] : 0;
        __syncthreads();
        tmp[threadIdx.x] += t;
        __syncthreads();
    }
    if (i < n) ex[i] = tmp[threadIdx.x] - v;           // exclusive within block
    if (threadIdx.x == 255) bsum[blockIdx.x] = tmp[255];
}

__global__ void k_scan2(int* __restrict__ bsum, int nb) {
    __shared__ int tmp[256];
    int v = (threadIdx.x < nb) ? bsum[threadIdx.x] : 0;
    tmp[threadIdx.x] = v;
    __syncthreads();
    for (int off = 1; off < 256; off <<= 1) {
        int t = (threadIdx.x >= off) ? tmp[threadIdx.x - off] : 0;
        __syncthreads();
        tmp[threadIdx.x] += t;
        __syncthreads();
    }
    if (threadIdx.x < nb) bsum[threadIdx.x] = tmp[threadIdx.x] - v;  // exclusive
}

__global__ void k_scan3(int* __restrict__ rp, const int* __restrict__ bsum,
                        int* __restrict__ cursor, int n, int E) {
    int i = blockIdx.x * 256 + threadIdx.x;
    if (i < n) {
        int r = rp[i] + bsum[blockIdx.x];
        rp[i] = r;
        cursor[i] = r;
    }
    if (i == 0) rp[n] = E;
}

__global__ void k_fill(const int* __restrict__ src, const int* __restrict__ dstv,
                       int* __restrict__ cursor, int* __restrict__ esrc, int E) {
    int e = blockIdx.x * 256 + threadIdx.x;
    if (e >= E) return;
    int d = dstv[e];
    int p = atomicAdd(&cursor[d], 1);
    esrc[p] = src[e];
}

// ---------------- attention, heads=2, d_head=64 (feature dim 128) ----------------
__global__ __launch_bounds__(256) void attn_h2(
    const float* __restrict__ Q, const float* __restrict__ Kf,
    const float* __restrict__ Vf, const float* __restrict__ Sf,
    const int* __restrict__ rowptr, const int* __restrict__ esrc,
    float* __restrict__ outp, int N)
{
    int wid = (blockIdx.x * blockDim.x + threadIdx.x) >> 6;
    int lane = threadIdx.x & 63;
    if (wid >= N) return;
    const size_t base = (size_t)wid * 128;
    float q0 = Q[base + lane] * 0.125f;        // alpha = q.k / sqrt(64)
    float q1 = Q[base + 64 + lane] * 0.125f;
    float m0 = -INFINITY, m1 = -INFINITY;
    float s0 = 0.f, s1 = 0.f, a0 = 0.f, a1 = 0.f;
    const int beg = rowptr[wid], end = rowptr[wid + 1];
    for (int e = beg; e < end; ++e) {
        int j = esrc[e];
        size_t jb = (size_t)j * 128;
        float p0 = q0 * Kf[jb + lane];
        float p1 = q1 * Kf[jb + 64 + lane];
        #pragma unroll
        for (int off = 32; off > 0; off >>= 1) {
            p0 += __shfl_xor(p0, off, 64);
            p1 += __shfl_xor(p1, off, 64);
        }
        float v0 = Vf[jb + lane];
        float v1 = Vf[jb + 64 + lane];
        float nm0 = fmaxf(m0, p0), nm1 = fmaxf(m1, p1);
        float f0 = __expf(m0 - nm0), f1 = __expf(m1 - nm1);
        float w0 = __expf(p0 - nm0), w1 = __expf(p1 - nm1);
        s0 = s0 * f0 + w0;       s1 = s1 * f1 + w1;
        a0 = a0 * f0 + w0 * v0;  a1 = a1 * f1 + w1 * v1;
        m0 = nm0; m1 = nm1;
    }
    float r0 = a0 / (s0 + 1e-16f) + Sf[base + lane];
    float r1 = a1 / (s1 + 1e-16f) + Sf[base + 64 + lane];
    outp[base + lane]      = fmaxf(r0, 0.f);   // relu after conv1 fused
    outp[base + 64 + lane] = fmaxf(r1, 0.f);
}

// ---------------- attention, heads=1, d_head=64 (feature dim 64) ----------------
__global__ __launch_bounds__(256) void attn_h1(
    const float* __restrict__ Q, const float* __restrict__ Kf,
    const float* __restrict__ Vf, const float* __restrict__ Sf,
    const int* __restrict__ rowptr, const int* __restrict__ esrc,
    float* __restrict__ outp, int N)
{
    int wid = (blockIdx.x * blockDim.x + threadIdx.x) >> 6;
    int lane = threadIdx.x & 63;
    if (wid >= N) return;
    const size_t base = (size_t)wid * 64;
    float q0 = Q[base + lane] * 0.125f;
    float m0 = -INFINITY, s0 = 0.f, a0 = 0.f;
    const int beg = rowptr[wid], end = rowptr[wid + 1];
    for (int e = beg; e < end; ++e) {
        int j = esrc[e];
        size_t jb = (size_t)j * 64;
        float p0 = q0 * Kf[jb + lane];
        #pragma unroll
        for (int off = 32; off > 0; off >>= 1) p0 += __shfl_xor(p0, off, 64);
        float v0 = Vf[jb + lane];
        float nm0 = fmaxf(m0, p0);
        float f0 = __expf(m0 - nm0);
        float w0 = __expf(p0 - nm0);
        s0 = s0 * f0 + w0;
        a0 = a0 * f0 + w0 * v0;
        m0 = nm0;
    }
    outp[base + lane] = a0 / (s0 + 1e-16f) + Sf[base + lane];  // no relu
}

// ---------------- global mean pool (batch is sorted) ----------------
__device__ __forceinline__ int lbound(const int* __restrict__ a, int n, int key) {
    int lo = 0, hi = n;
    while (lo < hi) {
        int mid = (lo + hi) >> 1;
        if (a[mid] < key) lo = mid + 1; else hi = mid;
    }
    return lo;
}

__global__ void pool_mean(const float* __restrict__ h, const int* __restrict__ batch,
                          float* __restrict__ pooled) {
    int g = blockIdx.x;
    int l = threadIdx.x;
    int lo = lbound(batch, NNODES, g);
    int hi = lbound(batch, NNODES, g + 1);
    float s0 = 0.f, s1 = 0.f, s2 = 0.f, s3 = 0.f;
    int i = lo;
    for (; i + 3 < hi; i += 4) {
        s0 += h[(size_t)(i + 0) * 64 + l];
        s1 += h[(size_t)(i + 1) * 64 + l];
        s2 += h[(size_t)(i + 2) * 64 + l];
        s3 += h[(size_t)(i + 3) * 64 + l];
    }
    for (; i < hi; ++i) s0 += h[(size_t)i * 64 + l];
    float cnt = (float)((hi - lo) > 1 ? (hi - lo) : 1);
    pooled[g * 64 + l] = (s0 + s1 + s2 + s3) / cnt;
}

// ---------------- head MLP: relu(pooled @ l1 + b1) @ l2 + b2 ----------------
__global__ void head_mlp(const float* __restrict__ pooled,
                         const float* __restrict__ l1W, const float* __restrict__ l1b,
                         const float* __restrict__ l2W, const float* __restrict__ l2b,
                         float* __restrict__ out) {
    int g = blockIdx.x;
    int l = threadIdx.x & 63;
    float p = pooled[g * 64 + l];
    float hsum = l1b[l];
    #pragma unroll
    for (int kk = 0; kk < 64; ++kk) {
        float pk = __shfl(p, kk, 64);
        hsum += pk * l1W[kk * 64 + l];
    }
    float h = fmaxf(hsum, 0.f);
    float o0 = h * l2W[l * 2 + 0];
    float o1 = h * l2W[l * 2 + 1];
    #pragma unroll
    for (int off = 32; off > 0; off >>= 1) {
        o0 += __shfl_xor(o0, off, 64);
        o1 += __shfl_xor(o1, off, 64);
    }
    if (l == 0) {
        out[g * 2 + 0] = o0 + l2b[0];
        out[g * 2 + 1] = o1 + l2b[1];
    }
}

// ---------------- host launch ----------------
extern "C" void kernel_launch(void* const* d_in, const int* in_sizes, int n_in,
                              void* d_out, int out_size, void* d_ws, size_t ws_size,
                              hipStream_t stream) {
    const float* x      = (const float*)d_in[0];
    const int*   ei     = (const int*)d_in[1];
    const int*   batch  = (const int*)d_in[2];
    const float* syn_W  = (const float*)d_in[3];  const float* syn_b = (const float*)d_in[4];
    const float* ant_W  = (const float*)d_in[5];  const float* ant_b = (const float*)d_in[6];
    const float* fus_W  = (const float*)d_in[7];  const float* fus_b = (const float*)d_in[8];
    const float* c1_Wq  = (const float*)d_in[9];  const float* c1_bq = (const float*)d_in[10];
    const float* c1_Wk  = (const float*)d_in[11]; const float* c1_bk = (const float*)d_in[12];
    const float* c1_Wv  = (const float*)d_in[13]; const float* c1_bv = (const float*)d_in[14];
    const float* c1_Ws  = (const float*)d_in[15]; const float* c1_bs = (const float*)d_in[16];
    const float* c2_Wq  = (const float*)d_in[17]; const float* c2_bq = (const float*)d_in[18];
    const float* c2_Wk  = (const float*)d_in[19]; const float* c2_bk = (const float*)d_in[20];
    const float* c2_Wv  = (const float*)d_in[21]; const float* c2_bv = (const float*)d_in[22];
    const float* c2_Ws  = (const float*)d_in[23]; const float* c2_bs = (const float*)d_in[24];
    const float* l1_W   = (const float*)d_in[25]; const float* l1_b  = (const float*)d_in[26];
    const float* l2_W   = (const float*)d_in[27]; const float* l2_b  = (const float*)d_in[28];
    const int* src = ei;
    const int* dst = ei + NEDGES;
    float* out = (float*)d_out;

    char* ws = (char*)d_ws;
    size_t off = 0;
    auto alloc = [&](size_t bytes) -> char* {
        char* p = ws + off;
        off += (bytes + 255) & ~((size_t)255);
        return p;
    };

    float* xfin   = (float*)alloc((size_t)NNODES * 128 * 4);  // syn||ant, later reused as H (conv1 out)
    float* xfus   = (float*)alloc((size_t)NNODES * 128 * 4);  // fused, later reused as H2 (conv2 out)
    float* Q1     = (float*)alloc((size_t)NNODES * 128 * 4);  // later q2
    float* K1     = (float*)alloc((size_t)NNODES * 128 * 4);  // later k2
    float* V1     = (float*)alloc((size_t)NNODES * 128 * 4);  // later v2
    float* S1     = (float*)alloc((size_t)NNODES * 128 * 4);  // later s2
    int*   deg    = (int*)alloc((NNODES + 1) * 4);
    int*   cursor = (int*)alloc((NNODES + 1) * 4);
    int*   rowptr = (int*)alloc((NNODES + 1) * 4);
    int*   bsum   = (int*)alloc(256 * 4);
    int*   esrc   = (int*)alloc((size_t)NEDGES * 4);
    float* pooled = (float*)alloc((size_t)NGRAPH * 64 * 4);

    const int MB = (NNODES + BM - 1) / BM;            // 782
    const int EB = (NEDGES + 255) / 256;              // 3125
    const int NB = (NNODES + 255) / 256;              // 196
    dim3 t256(256);

    // --- CSR build ---
    hipMemsetAsync(deg, 0, (NNODES + 1) * sizeof(int), stream);
    k_hist<<<EB, t256, 0, stream>>>(dst, deg, NEDGES);
    k_scan1<<<NB, t256, 0, stream>>>(deg, rowptr, bsum, NNODES);
    k_scan2<<<1, t256, 0, stream>>>(bsum, NB);
    k_scan3<<<NB, t256, 0, stream>>>(rowptr, bsum, cursor, NNODES, NEDGES);
    k_fill<<<EB, t256, 0, stream>>>(src, dst, cursor, esrc, NEDGES);

    // --- encoders: xfin = [relu(x@syn_W+b) || relu(x@ant_W+b)] ---
    gemm_bias_act<<<dim3(MB, 1), t256, 0, stream>>>(x, INC, NNODES, INC, syn_W, 64, syn_b, xfin, 128, 0,  1);
    gemm_bias_act<<<dim3(MB, 1), t256, 0, stream>>>(x, INC, NNODES, INC, ant_W, 64, ant_b, xfin, 128, 64, 1);
    // --- fusion: xfus = xfin @ fus_W + b ---
    gemm_bias_act<<<dim3(MB, 2), t256, 0, stream>>>(xfin, 128, NNODES, 128, fus_W, 128, fus_b, xfus, 128, 0, 0);

    // --- conv1 linears ---
    gemm_bias_act<<<dim3(MB, 2), t256, 0, stream>>>(xfus, 128, NNODES, 128, c1_Wq, 128, c1_bq, Q1, 128, 0, 0);
    gemm_bias_act<<<dim3(MB, 2), t256, 0, stream>>>(xfus, 128, NNODES, 128, c1_Wk, 128, c1_bk, K1, 128, 0, 0);
    gemm_bias_act<<<dim3(MB, 2), t256, 0, stream>>>(xfus, 128, NNODES, 128, c1_Wv, 128, c1_bv, V1, 128, 0, 0);
    gemm_bias_act<<<dim3(MB, 2), t256, 0, stream>>>(xfus, 128, NNODES, 128, c1_Ws, 128, c1_bs, S1, 128, 0, 0);

    // --- conv1 attention + relu -> H (reuse xfin) ---
    float* H = xfin;
    attn_h2<<<(NNODES * 64 + 255) / 256, t256, 0, stream>>>(Q1, K1, V1, S1, rowptr, esrc, H, NNODES);

    // --- conv2 linears (reuse Q1..S1 buffers, stride 64) ---
    float* q2 = Q1; float* k2 = K1; float* v2 = V1; float* s2 = S1;
    gemm_bias_act<<<dim3(MB, 1), t256, 0, stream>>>(H, 128, NNODES, 128, c2_Wq, 64, c2_bq, q2, 64, 0, 0);
    gemm_bias_act<<<dim3(MB, 1), t256, 0, stream>>>(H, 128, NNODES, 128, c2_Wk, 64, c2_bk, k2, 64, 0, 0);
    gemm_bias_act<<<dim3(MB, 1), t256, 0, stream>>>(H, 128, NNODES, 128, c2_Wv, 64, c2_bv, v2, 64, 0, 0);
    gemm_bias_act<<<dim3(MB, 1), t256, 0, stream>>>(H, 128, NNODES, 128, c2_Ws, 64, c2_bs, s2, 64, 0, 0);

    // --- conv2 attention -> H2 (reuse xfus) ---
    float* H2 = xfus;
    attn_h1<<<(NNODES * 64 + 255) / 256, t256, 0, stream>>>(q2, k2, v2, s2, rowptr, esrc, H2, NNODES);

    // --- pool + head ---
    pool_mean<<<NGRAPH, 64, 0, stream>>>(H2, batch, pooled);
    head_mlp<<<NGRAPH, 64, 0, stream>>>(pooled, l1_W, l1_b, l2_W, l2_b, out);
}

// Round 2
// 470.055 us; speedup vs baseline: 1.7282x; 1.7282x over previous
//
#include <hip/hip_runtime.h>
#include <math.h>

#define NNODES 50000
#define NEDGES 800000
#define INC    300
#define NGRAPH 256

typedef __attribute__((ext_vector_type(8))) short bf16x8;
typedef __attribute__((ext_vector_type(4))) short bf16x4;
typedef __attribute__((ext_vector_type(4))) float f32x4;

__device__ __forceinline__ unsigned short f2bf(float f) {
    unsigned u = __float_as_uint(f);
    u += 0x7fffu + ((u >> 16) & 1u);
    return (unsigned short)(u >> 16);
}
__device__ __forceinline__ float bf2f(unsigned short h) {
    return __uint_as_float(((unsigned)h) << 16);
}

// ---------------- weight transpose+cast: W[K][N] f32 -> Wt[N][K] bf16 ----------------
struct WTArgs {
    const float* w[11];
    unsigned short* o[11];
    int K[11];
    int N[11];
};

__global__ void k_wt(WTArgs args) {
    int which = blockIdx.y;
    int i = blockIdx.x * 256 + threadIdx.x;
    int K = args.K[which], N = args.N[which];
    if (i >= K * N) return;
    int k = i / N, n = i - k * N;
    args.o[which][(size_t)n * K + k] = f2bf(args.w[which][i]);
}

// ---------------- MFMA GEMM: C[M,N] = act(A[M,K] @ Wt^T + bias) ----------------
// A: f32 row-major [M][lda]; Wt: bf16 [N][K] (pre-transposed weights)
// Output: Cf (f32) and/or Cb (bf16), stride ldc, column offset c0.
#define BM 128
#define BN 64
#define BK 64
#define LDP 72   // padded LDS leading dim (bf16 elems)

__global__ __launch_bounds__(256) void gemm_mfma(
    const float* __restrict__ A, int lda, int M, int K,
    const unsigned short* __restrict__ Wt,
    const float* __restrict__ bias,
    float* __restrict__ Cf, unsigned short* __restrict__ Cb,
    int ldc, int c0, int relu)
{
    __shared__ __align__(16) short As[BM * LDP];
    __shared__ __align__(16) short Bs[BN * LDP];
    const int tid = threadIdx.x;
    const int bm = blockIdx.x * BM;
    const int bn = blockIdx.y * BN;
    const int tr = tid >> 4;          // 0..15
    const int tc = (tid & 15) * 4;    // 0..60
    const int l  = tid & 63;
    const int wv = tid >> 6;          // wave 0..3
    const int fr = l & 15;
    const int fg = l >> 4;            // 0..3

    f32x4 acc[2][4];
    #pragma unroll
    for (int i = 0; i < 2; ++i)
        #pragma unroll
        for (int j = 0; j < 4; ++j) acc[i][j] = (f32x4){0.f, 0.f, 0.f, 0.f};

    for (int k0 = 0; k0 < K; k0 += BK) {
        // stage A tile (f32 -> bf16), 128x64
        #pragma unroll
        for (int p = 0; p < 8; ++p) {
            int row = p * 16 + tr;
            int grow = bm + row;
            int k = k0 + tc;
            float x0 = 0.f, x1 = 0.f, x2 = 0.f, x3 = 0.f;
            if (grow < M) {
                if (k + 4 <= K) {
                    float4 a4 = *reinterpret_cast<const float4*>(A + (size_t)grow * lda + k);
                    x0 = a4.x; x1 = a4.y; x2 = a4.z; x3 = a4.w;
                } else {
                    if (k + 0 < K) x0 = A[(size_t)grow * lda + k + 0];
                    if (k + 1 < K) x1 = A[(size_t)grow * lda + k + 1];
                    if (k + 2 < K) x2 = A[(size_t)grow * lda + k + 2];
                    if (k + 3 < K) x3 = A[(size_t)grow * lda + k + 3];
                }
            }
            bf16x4 s4 = { (short)f2bf(x0), (short)f2bf(x1), (short)f2bf(x2), (short)f2bf(x3) };
            *reinterpret_cast<bf16x4*>(As + row * LDP + tc) = s4;
        }
        // stage Wt tile (bf16), 64 rows (=out cols) x 64 k
        #pragma unroll
        for (int p = 0; p < 4; ++p) {
            int n = p * 16 + tr;
            int k = k0 + tc;
            bf16x4 s4;
            if (k + 4 <= K) {
                s4 = *reinterpret_cast<const bf16x4*>(Wt + (size_t)(bn + n) * K + k);
            } else {
                short e0 = 0, e1 = 0, e2 = 0, e3 = 0;
                if (k + 0 < K) e0 = (short)Wt[(size_t)(bn + n) * K + k + 0];
                if (k + 1 < K) e1 = (short)Wt[(size_t)(bn + n) * K + k + 1];
                if (k + 2 < K) e2 = (short)Wt[(size_t)(bn + n) * K + k + 2];
                if (k + 3 < K) e3 = (short)Wt[(size_t)(bn + n) * K + k + 3];
                s4 = (bf16x4){ e0, e1, e2, e3 };
            }
            *reinterpret_cast<bf16x4*>(Bs + n * LDP + tc) = s4;
        }
        __syncthreads();
        #pragma unroll
        for (int ks = 0; ks < 2; ++ks) {
            int kk = ks * 32 + fg * 8;
            bf16x8 a0 = *reinterpret_cast<const bf16x8*>(As + (wv * 32 + fr) * LDP + kk);
            bf16x8 a1 = *reinterpret_cast<const bf16x8*>(As + (wv * 32 + 16 + fr) * LDP + kk);
            #pragma unroll
            for (int nj = 0; nj < 4; ++nj) {
                bf16x8 b = *reinterpret_cast<const bf16x8*>(Bs + (nj * 16 + fr) * LDP + kk);
                acc[0][nj] = __builtin_amdgcn_mfma_f32_16x16x32_bf16(a0, b, acc[0][nj], 0, 0, 0);
                acc[1][nj] = __builtin_amdgcn_mfma_f32_16x16x32_bf16(a1, b, acc[1][nj], 0, 0, 0);
            }
        }
        __syncthreads();
    }
    // epilogue: C/D layout col=lane&15, row=(lane>>4)*4+reg (m89-verified)
    #pragma unroll
    for (int mi = 0; mi < 2; ++mi) {
        int row0 = bm + wv * 32 + mi * 16 + fg * 4;
        #pragma unroll
        for (int nj = 0; nj < 4; ++nj) {
            int col = bn + nj * 16 + fr;
            float bv = bias[col];
            #pragma unroll
            for (int r = 0; r < 4; ++r) {
                int gr = row0 + r;
                if (gr >= M) continue;
                float val = acc[mi][nj][r] + bv;
                if (relu) val = fmaxf(val, 0.f);
                if (Cf) Cf[(size_t)gr * ldc + c0 + col] = val;
                if (Cb) Cb[(size_t)gr * ldc + c0 + col] = f2bf(val);
            }
        }
    }
}

// ---------------- CSR build (group edges by dst) ----------------
__global__ void k_hist(const int* __restrict__ dstv, int* __restrict__ deg, int E) {
    int e = blockIdx.x * 256 + threadIdx.x;
    if (e < E) atomicAdd(&deg[dstv[e]], 1);
}

__global__ void k_scan1(const int* __restrict__ deg, int* __restrict__ ex,
                        int* __restrict__ bsum, int n) {
    __shared__ int tmp[256];
    int i = blockIdx.x * 256 + threadIdx.x;
    int v = (i < n) ? deg[i] : 0;
    tmp[threadIdx.x] = v;
    __syncthreads();
    for (int off = 1; off < 256; off <<= 1) {
        int t = (threadIdx.x >= off) ? tmp[threadIdx.x - off] : 0;
        __syncthreads();
        tmp[threadIdx.x] += t;
        __syncthreads();
    }
    if (i < n) ex[i] = tmp[threadIdx.x] - v;
    if (threadIdx.x == 255) bsum[blockIdx.x] = tmp[255];
}

__global__ void k_scan2(int* __restrict__ bsum, int nb) {
    __shared__ int tmp[256];
    int v = (threadIdx.x < nb) ? bsum[threadIdx.x] : 0;
    tmp[threadIdx.x] = v;
    __syncthreads();
    for (int off = 1; off < 256; off <<= 1) {
        int t = (threadIdx.x >= off) ? tmp[threadIdx.x - off] : 0;
        __syncthreads();
        tmp[threadIdx.x] += t;
        __syncthreads();
    }
    if (threadIdx.x < nb) bsum[threadIdx.x] = tmp[threadIdx.x] - v;
}

__global__ void k_scan3(int* __restrict__ rp, const int* __restrict__ bsum,
                        int* __restrict__ cursor, int n, int E) {
    int i = blockIdx.x * 256 + threadIdx.x;
    if (i < n) {
        int r = rp[i] + bsum[blockIdx.x];
        rp[i] = r;
        cursor[i] = r;
    }
    if (i == 0) rp[n] = E;
}

__global__ void k_fill(const int* __restrict__ src, const int* __restrict__ dstv,
                       int* __restrict__ cursor, int* __restrict__ esrc, int E) {
    int e = blockIdx.x * 256 + threadIdx.x;
    if (e >= E) return;
    int d = dstv[e];
    int p = atomicAdd(&cursor[d], 1);
    esrc[p] = src[e];
}

// ---------------- attention, heads=2, d_head=64 ----------------
// Lane l owns elems {2l, 2l+1}; lanes 0-31 = head0, 32-63 = head1.
__global__ __launch_bounds__(256) void attn_h2(
    const float* __restrict__ Q, const unsigned short* __restrict__ Kb,
    const unsigned short* __restrict__ Vb, const float* __restrict__ Sf,
    const int* __restrict__ rowptr, const int* __restrict__ esrc,
    float* __restrict__ outp, int N)
{
    int wid = (blockIdx.x * blockDim.x + threadIdx.x) >> 6;
    int l = threadIdx.x & 63;
    if (wid >= N) return;
    const size_t base = (size_t)wid * 128;
    float2 qv = *reinterpret_cast<const float2*>(Q + base + 2 * l);
    float q0 = qv.x * 0.125f, q1 = qv.y * 0.125f;
    float m = -1e30f, s = 0.f, a0 = 0.f, a1 = 0.f;
    const int beg = rowptr[wid], end = rowptr[wid + 1];
    int e = beg;
    for (; e + 1 < end; e += 2) {
        int j0 = esrc[e], j1 = esrc[e + 1];
        ushort2 ka = *reinterpret_cast<const ushort2*>(Kb + (size_t)j0 * 128 + 2 * l);
        ushort2 kc = *reinterpret_cast<const ushort2*>(Kb + (size_t)j1 * 128 + 2 * l);
        ushort2 va = *reinterpret_cast<const ushort2*>(Vb + (size_t)j0 * 128 + 2 * l);
        ushort2 vc = *reinterpret_cast<const ushort2*>(Vb + (size_t)j1 * 128 + 2 * l);
        float p0 = q0 * bf2f(ka.x) + q1 * bf2f(ka.y);
        float p1 = q0 * bf2f(kc.x) + q1 * bf2f(kc.y);
        #pragma unroll
        for (int off = 16; off > 0; off >>= 1) {
            p0 += __shfl_xor(p0, off, 64);
            p1 += __shfl_xor(p1, off, 64);
        }
        float nm = fmaxf(m, p0);
        float f  = __expf(m - nm);
        float w  = __expf(p0 - nm);
        s = s * f + w; a0 = a0 * f + w * bf2f(va.x); a1 = a1 * f + w * bf2f(va.y); m = nm;
        nm = fmaxf(m, p1);
        f  = __expf(m - nm);
        w  = __expf(p1 - nm);
        s = s * f + w; a0 = a0 * f + w * bf2f(vc.x); a1 = a1 * f + w * bf2f(vc.y); m = nm;
    }
    if (e < end) {
        int j0 = esrc[e];
        ushort2 ka = *reinterpret_cast<const ushort2*>(Kb + (size_t)j0 * 128 + 2 * l);
        ushort2 va = *reinterpret_cast<const ushort2*>(Vb + (size_t)j0 * 128 + 2 * l);
        float p0 = q0 * bf2f(ka.x) + q1 * bf2f(ka.y);
        #pragma unroll
        for (int off = 16; off > 0; off >>= 1) p0 += __shfl_xor(p0, off, 64);
        float nm = fmaxf(m, p0);
        float f  = __expf(m - nm);
        float w  = __expf(p0 - nm);
        s = s * f + w; a0 = a0 * f + w * bf2f(va.x); a1 = a1 * f + w * bf2f(va.y); m = nm;
    }
    float inv = 1.f / (s + 1e-16f);
    float2 sv = *reinterpret_cast<const float2*>(Sf + base + 2 * l);
    float r0 = fmaxf(a0 * inv + sv.x, 0.f);   // relu fused (post-conv1)
    float r1 = fmaxf(a1 * inv + sv.y, 0.f);
    *reinterpret_cast<float2*>(outp + base + 2 * l) = make_float2(r0, r1);
}

// ---------------- attention, heads=1, d=64; 2 edges in flight (one per 32-lane half) ----------------
__global__ __launch_bounds__(256) void attn_h1(
    const float* __restrict__ Q, const unsigned short* __restrict__ Kb,
    const unsigned short* __restrict__ Vb, const float* __restrict__ Sf,
    const int* __restrict__ rowptr, const int* __restrict__ esrc,
    float* __restrict__ outp, int N)
{
    int wid = (blockIdx.x * blockDim.x + threadIdx.x) >> 6;
    int l = threadIdx.x & 63;
    if (wid >= N) return;
    int li = l & 31, h = l >> 5;
    const size_t base = (size_t)wid * 64;
    float q0 = Q[base + 2 * li] * 0.125f;
    float q1 = Q[base + 2 * li + 1] * 0.125f;
    float m = -1e30f, s = 0.f, a0 = 0.f, a1 = 0.f;
    const int beg = rowptr[wid], end = rowptr[wid + 1];
    int deg = end - beg;
    int iters = (deg + 1) >> 1;
    for (int it = 0; it < iters; ++it) {
        int e = beg + 2 * it + h;
        bool valid = e < end;
        int j = valid ? esrc[e] : esrc[beg];
        ushort2 kv = *reinterpret_cast<const ushort2*>(Kb + (size_t)j * 64 + 2 * li);
        ushort2 vv = *reinterpret_cast<const ushort2*>(Vb + (size_t)j * 64 + 2 * li);
        float p = q0 * bf2f(kv.x) + q1 * bf2f(kv.y);
        #pragma unroll
        for (int off = 16; off > 0; off >>= 1) p += __shfl_xor(p, off, 64);
        float nm = valid ? fmaxf(m, p) : m;
        float f  = __expf(m - nm);
        float w  = valid ? __expf(p - nm) : 0.f;
        s = s * f + w; a0 = a0 * f + w * bf2f(vv.x); a1 = a1 * f + w * bf2f(vv.y); m = nm;
    }
    // merge the two halves' online-softmax states
    float om  = __shfl_xor(m, 32, 64);
    float M_  = fmaxf(m, om);
    float fm  = __expf(m - M_);
    float ofm = __expf(om - M_);
    float os  = __shfl_xor(s, 32, 64);
    float oa0 = __shfl_xor(a0, 32, 64);
    float oa1 = __shfl_xor(a1, 32, 64);
    float St = s * fm + os * ofm;
    float A0 = a0 * fm + oa0 * ofm;
    float A1 = a1 * fm + oa1 * ofm;
    if (h == 0) {
        float inv = 1.f / (St + 1e-16f);
        float r0 = A0 * inv + Sf[base + 2 * li];
        float r1 = A1 * inv + Sf[base + 2 * li + 1];
        *reinterpret_cast<float2*>(outp + base + 2 * li) = make_float2(r0, r1);
    }
}

// ---------------- global mean pool (batch is sorted) ----------------
__device__ __forceinline__ int lbound(const int* __restrict__ a, int n, int key) {
    int lo = 0, hi = n;
    while (lo < hi) {
        int mid = (lo + hi) >> 1;
        if (a[mid] < key) lo = mid + 1; else hi = mid;
    }
    return lo;
}

__global__ void pool_mean(const float* __restrict__ h, const int* __restrict__ batch,
                          float* __restrict__ pooled) {
    int g = blockIdx.x;
    int l = threadIdx.x;
    int lo = lbound(batch, NNODES, g);
    int hi = lbound(batch, NNODES, g + 1);
    float s0 = 0.f, s1 = 0.f, s2 = 0.f, s3 = 0.f;
    int i = lo;
    for (; i + 3 < hi; i += 4) {
        s0 += h[(size_t)(i + 0) * 64 + l];
        s1 += h[(size_t)(i + 1) * 64 + l];
        s2 += h[(size_t)(i + 2) * 64 + l];
        s3 += h[(size_t)(i + 3) * 64 + l];
    }
    for (; i < hi; ++i) s0 += h[(size_t)i * 64 + l];
    float cnt = (float)((hi - lo) > 1 ? (hi - lo) : 1);
    pooled[g * 64 + l] = (s0 + s1 + s2 + s3) / cnt;
}

// ---------------- head MLP ----------------
__global__ void head_mlp(const float* __restrict__ pooled,
                         const float* __restrict__ l1W, const float* __restrict__ l1b,
                         const float* __restrict__ l2W, const float* __restrict__ l2b,
                         float* __restrict__ out) {
    int g = blockIdx.x;
    int l = threadIdx.x & 63;
    float p = pooled[g * 64 + l];
    float hsum = l1b[l];
    #pragma unroll
    for (int kk = 0; kk < 64; ++kk) {
        float pk = __shfl(p, kk, 64);
        hsum += pk * l1W[kk * 64 + l];
    }
    float h = fmaxf(hsum, 0.f);
    float o0 = h * l2W[l * 2 + 0];
    float o1 = h * l2W[l * 2 + 1];
    #pragma unroll
    for (int off = 32; off > 0; off >>= 1) {
        o0 += __shfl_xor(o0, off, 64);
        o1 += __shfl_xor(o1, off, 64);
    }
    if (l == 0) {
        out[g * 2 + 0] = o0 + l2b[0];
        out[g * 2 + 1] = o1 + l2b[1];
    }
}

// ---------------- host launch ----------------
extern "C" void kernel_launch(void* const* d_in, const int* in_sizes, int n_in,
                              void* d_out, int out_size, void* d_ws, size_t ws_size,
                              hipStream_t stream) {
    const float* x      = (const float*)d_in[0];
    const int*   ei     = (const int*)d_in[1];
    const int*   batch  = (const int*)d_in[2];
    const float* syn_W  = (const float*)d_in[3];  const float* syn_b = (const float*)d_in[4];
    const float* ant_W  = (const float*)d_in[5];  const float* ant_b = (const float*)d_in[6];
    const float* fus_W  = (const float*)d_in[7];  const float* fus_b = (const float*)d_in[8];
    const float* c1_Wq  = (const float*)d_in[9];  const float* c1_bq = (const float*)d_in[10];
    const float* c1_Wk  = (const float*)d_in[11]; const float* c1_bk = (const float*)d_in[12];
    const float* c1_Wv  = (const float*)d_in[13]; const float* c1_bv = (const float*)d_in[14];
    const float* c1_Ws  = (const float*)d_in[15]; const float* c1_bs = (const float*)d_in[16];
    const float* c2_Wq  = (const float*)d_in[17]; const float* c2_bq = (const float*)d_in[18];
    const float* c2_Wk  = (const float*)d_in[19]; const float* c2_bk = (const float*)d_in[20];
    const float* c2_Wv  = (const float*)d_in[21]; const float* c2_bv = (const float*)d_in[22];
    const float* c2_Ws  = (const float*)d_in[23]; const float* c2_bs = (const float*)d_in[24];
    const float* l1_W   = (const float*)d_in[25]; const float* l1_b  = (const float*)d_in[26];
    const float* l2_W   = (const float*)d_in[27]; const float* l2_b  = (const float*)d_in[28];
    const int* src = ei;
    const int* dst = ei + NEDGES;
    float* out = (float*)d_out;

    char* ws = (char*)d_ws;
    size_t off = 0;
    auto alloc = [&](size_t bytes) -> char* {
        char* p = ws + off;
        off += (bytes + 255) & ~((size_t)255);
        return p;
    };

    float* xfin = (float*)alloc((size_t)NNODES * 128 * 4);   // enc out; later H
    float* xfus = (float*)alloc((size_t)NNODES * 128 * 4);   // fused; later H2
    float* Q1   = (float*)alloc((size_t)NNODES * 128 * 4);   // later q2 (stride 64)
    float* S1   = (float*)alloc((size_t)NNODES * 128 * 4);   // later s2
    unsigned short* K1b = (unsigned short*)alloc((size_t)NNODES * 128 * 2);  // later k2b
    unsigned short* V1b = (unsigned short*)alloc((size_t)NNODES * 128 * 2);  // later v2b
    unsigned short* syn_t = (unsigned short*)alloc(64 * 300 * 2);
    unsigned short* ant_t = (unsigned short*)alloc(64 * 300 * 2);
    unsigned short* fus_t = (unsigned short*)alloc(128 * 128 * 2);
    unsigned short* c1q_t = (unsigned short*)alloc(128 * 128 * 2);
    unsigned short* c1k_t = (unsigned short*)alloc(128 * 128 * 2);
    unsigned short* c1v_t = (unsigned short*)alloc(128 * 128 * 2);
    unsigned short* c1s_t = (unsigned short*)alloc(128 * 128 * 2);
    unsigned short* c2q_t = (unsigned short*)alloc(64 * 128 * 2);
    unsigned short* c2k_t = (unsigned short*)alloc(64 * 128 * 2);
    unsigned short* c2v_t = (unsigned short*)alloc(64 * 128 * 2);
    unsigned short* c2s_t = (unsigned short*)alloc(64 * 128 * 2);
    int*   deg    = (int*)alloc((NNODES + 1) * 4);
    int*   cursor = (int*)alloc((NNODES + 1) * 4);
    int*   rowptr = (int*)alloc((NNODES + 1) * 4);
    int*   bsum   = (int*)alloc(256 * 4);
    int*   esrc   = (int*)alloc((size_t)NEDGES * 4);
    float* pooled = (float*)alloc((size_t)NGRAPH * 64 * 4);

    const int MB = (NNODES + BM - 1) / BM;   // 391
    const int EB = (NEDGES + 255) / 256;
    const int NB = (NNODES + 255) / 256;
    dim3 t256(256);

    // --- weight transposes (one fused launch) ---
    WTArgs wa;
    wa.w[0] = syn_W;  wa.o[0] = syn_t;  wa.K[0] = 300; wa.N[0] = 64;
    wa.w[1] = ant_W;  wa.o[1] = ant_t;  wa.K[1] = 300; wa.N[1] = 64;
    wa.w[2] = fus_W;  wa.o[2] = fus_t;  wa.K[2] = 128; wa.N[2] = 128;
    wa.w[3] = c1_Wq;  wa.o[3] = c1q_t;  wa.K[3] = 128; wa.N[3] = 128;
    wa.w[4] = c1_Wk;  wa.o[4] = c1k_t;  wa.K[4] = 128; wa.N[4] = 128;
    wa.w[5] = c1_Wv;  wa.o[5] = c1v_t;  wa.K[5] = 128; wa.N[5] = 128;
    wa.w[6] = c1_Ws;  wa.o[6] = c1s_t;  wa.K[6] = 128; wa.N[6] = 128;
    wa.w[7] = c2_Wq;  wa.o[7] = c2q_t;  wa.K[7] = 128; wa.N[7] = 64;
    wa.w[8] = c2_Wk;  wa.o[8] = c2k_t;  wa.K[8] = 128; wa.N[8] = 64;
    wa.w[9] = c2_Wv;  wa.o[9] = c2v_t;  wa.K[9] = 128; wa.N[9] = 64;
    wa.w[10] = c2_Ws; wa.o[10] = c2s_t; wa.K[10] = 128; wa.N[10] = 64;
    k_wt<<<dim3(75, 11), t256, 0, stream>>>(wa);

    // --- CSR build ---
    hipMemsetAsync(deg, 0, (NNODES + 1) * sizeof(int), stream);
    k_hist<<<EB, t256, 0, stream>>>(dst, deg, NEDGES);
    k_scan1<<<NB, t256, 0, stream>>>(deg, rowptr, bsum, NNODES);
    k_scan2<<<1, t256, 0, stream>>>(bsum, NB);
    k_scan3<<<NB, t256, 0, stream>>>(rowptr, bsum, cursor, NNODES, NEDGES);
    k_fill<<<EB, t256, 0, stream>>>(src, dst, cursor, esrc, NEDGES);

    // --- encoders ---
    gemm_mfma<<<dim3(MB, 1), t256, 0, stream>>>(x, INC, NNODES, INC, syn_t, syn_b, xfin, nullptr, 128, 0, 1);
    gemm_mfma<<<dim3(MB, 1), t256, 0, stream>>>(x, INC, NNODES, INC, ant_t, ant_b, xfin, nullptr, 128, 64, 1);
    // --- fusion ---
    gemm_mfma<<<dim3(MB, 2), t256, 0, stream>>>(xfin, 128, NNODES, 128, fus_t, fus_b, xfus, nullptr, 128, 0, 0);

    // --- conv1 linears (K,V straight to bf16 gather tables) ---
    gemm_mfma<<<dim3(MB, 2), t256, 0, stream>>>(xfus, 128, NNODES, 128, c1q_t, c1_bq, Q1, nullptr, 128, 0, 0);
    gemm_mfma<<<dim3(MB, 2), t256, 0, stream>>>(xfus, 128, NNODES, 128, c1k_t, c1_bk, nullptr, K1b, 128, 0, 0);
    gemm_mfma<<<dim3(MB, 2), t256, 0, stream>>>(xfus, 128, NNODES, 128, c1v_t, c1_bv, nullptr, V1b, 128, 0, 0);
    gemm_mfma<<<dim3(MB, 2), t256, 0, stream>>>(xfus, 128, NNODES, 128, c1s_t, c1_bs, S1, nullptr, 128, 0, 0);

    // --- conv1 attention + relu -> H ---
    float* H = xfin;
    attn_h2<<<(NNODES * 64 + 255) / 256, t256, 0, stream>>>(Q1, K1b, V1b, S1, rowptr, esrc, H, NNODES);

    // --- conv2 linears (reuse buffers, stride 64) ---
    float* q2 = Q1; float* s2 = S1;
    unsigned short* k2b = K1b; unsigned short* v2b = V1b;
    gemm_mfma<<<dim3(MB, 1), t256, 0, stream>>>(H, 128, NNODES, 128, c2q_t, c2_bq, q2, nullptr, 64, 0, 0);
    gemm_mfma<<<dim3(MB, 1), t256, 0, stream>>>(H, 128, NNODES, 128, c2k_t, c2_bk, nullptr, k2b, 64, 0, 0);
    gemm_mfma<<<dim3(MB, 1), t256, 0, stream>>>(H, 128, NNODES, 128, c2v_t, c2_bv, nullptr, v2b, 64, 0, 0);
    gemm_mfma<<<dim3(MB, 1), t256, 0, stream>>>(H, 128, NNODES, 128, c2s_t, c2_bs, s2, nullptr, 64, 0, 0);

    // --- conv2 attention -> H2 ---
    float* H2 = xfus;
    attn_h1<<<(NNODES * 64 + 255) / 256, t256, 0, stream>>>(q2, k2b, v2b, s2, rowptr, esrc, H2, NNODES);

    // --- pool + head ---
    pool_mean<<<NGRAPH, 64, 0, stream>>>(H2, batch, pooled);
    head_mlp<<<NGRAPH, 64, 0, stream>>>(pooled, l1_W, l1_b, l2_W, l2_b, out);
}

// Round 3
// 382.285 us; speedup vs baseline: 2.1249x; 1.2296x over previous
//
#include <hip/hip_runtime.h>
#include <math.h>

#define NNODES 50000
#define NEDGES 800000
#define INC    300
#define NGRAPH 256

typedef __attribute__((ext_vector_type(8))) short bf16x8;
typedef __attribute__((ext_vector_type(4))) short bf16x4;
typedef __attribute__((ext_vector_type(4))) float f32x4;

__device__ __forceinline__ unsigned short f2bf(float f) {
    unsigned u = __float_as_uint(f);
    u += 0x7fffu + ((u >> 16) & 1u);
    return (unsigned short)(u >> 16);
}
__device__ __forceinline__ float bf2f(unsigned short h) {
    return __uint_as_float(((unsigned)h) << 16);
}

// ---------------- weight transpose+cast: W[K][N] f32 -> Wt[N][K] bf16 ----------------
struct WTArgs {
    const float* w[11];
    unsigned short* o[11];
    int K[11];
    int N[11];
};

__global__ void k_wt(WTArgs args) {
    int which = blockIdx.y;
    int i = blockIdx.x * 256 + threadIdx.x;
    int K = args.K[which], N = args.N[which];
    if (i >= K * N) return;
    int k = i / N, n = i - k * N;
    args.o[which][(size_t)n * K + k] = f2bf(args.w[which][i]);
}

// ---------------- bias concat ----------------
struct BiasArgs {
    const float* syn_b; const float* ant_b;
    const float* c1q; const float* c1k; const float* c1v; const float* c1s;
    const float* c2q; const float* c2k; const float* c2v; const float* c2s;
    float* enc_b;   // [128]
    float* c1_b;    // [512]
    float* c2_b;    // [256]
};

__global__ void k_bias(BiasArgs a) {
    int t = threadIdx.x;  // 1024
    if (t < 512) {
        int s = t >> 7, r = t & 127;
        const float* p = (s == 0) ? a.c1q : (s == 1) ? a.c1k : (s == 2) ? a.c1v : a.c1s;
        a.c1_b[t] = p[r];
    } else if (t < 768) {
        int u = t - 512;
        int s = u >> 6, r = u & 63;
        const float* p = (s == 0) ? a.c2q : (s == 1) ? a.c2k : (s == 2) ? a.c2v : a.c2s;
        a.c2_b[u] = p[r];
    } else if (t < 896) {
        int u = t - 768;
        a.enc_b[u] = (u < 64) ? a.syn_b[u] : a.ant_b[u - 64];
    }
}

// ---------------- MFMA GEMM: C[M,N] = act(A[M,K] @ Wt^T + bias), C in bf16 ----------------
// A: row-major [M][lda], f32 or bf16 per template; Wt: bf16 [N][K]
#define BM 128
#define BN 64
#define BK 64
#define LDP 72   // padded LDS leading dim (bf16 elems)

template<bool ABF16>
__global__ __launch_bounds__(256) void gemm_mfma(
    const void* __restrict__ Av, int lda, int M, int K,
    const unsigned short* __restrict__ Wt,
    const float* __restrict__ bias,
    unsigned short* __restrict__ C, int ldc, int relu)
{
    __shared__ __align__(16) short As[BM * LDP];
    __shared__ __align__(16) short Bs[BN * LDP];
    const int tid = threadIdx.x;
    const int bm = blockIdx.x * BM;
    const int bn = blockIdx.y * BN;
    const int tr = tid >> 4;          // 0..15
    const int tc = (tid & 15) * 4;    // 0..60
    const int l  = tid & 63;
    const int wv = tid >> 6;          // wave 0..3
    const int fr = l & 15;
    const int fg = l >> 4;            // 0..3

    f32x4 acc[2][4];
    #pragma unroll
    for (int i = 0; i < 2; ++i)
        #pragma unroll
        for (int j = 0; j < 4; ++j) acc[i][j] = (f32x4){0.f, 0.f, 0.f, 0.f};

    for (int k0 = 0; k0 < K; k0 += BK) {
        // stage A tile, 128x64 (convert to bf16 if f32 input)
        #pragma unroll
        for (int p = 0; p < 8; ++p) {
            int row = p * 16 + tr;
            int grow = bm + row;
            int k = k0 + tc;
            bf16x4 s4;
            if constexpr (ABF16) {
                const unsigned short* A = (const unsigned short*)Av;
                if (grow < M && k + 4 <= K) {
                    s4 = *reinterpret_cast<const bf16x4*>(A + (size_t)grow * lda + k);
                } else {
                    short e0 = 0, e1 = 0, e2 = 0, e3 = 0;
                    if (grow < M) {
                        if (k + 0 < K) e0 = (short)A[(size_t)grow * lda + k + 0];
                        if (k + 1 < K) e1 = (short)A[(size_t)grow * lda + k + 1];
                        if (k + 2 < K) e2 = (short)A[(size_t)grow * lda + k + 2];
                        if (k + 3 < K) e3 = (short)A[(size_t)grow * lda + k + 3];
                    }
                    s4 = (bf16x4){ e0, e1, e2, e3 };
                }
            } else {
                const float* A = (const float*)Av;
                float x0 = 0.f, x1 = 0.f, x2 = 0.f, x3 = 0.f;
                if (grow < M) {
                    if (k + 4 <= K) {
                        float4 a4 = *reinterpret_cast<const float4*>(A + (size_t)grow * lda + k);
                        x0 = a4.x; x1 = a4.y; x2 = a4.z; x3 = a4.w;
                    } else {
                        if (k + 0 < K) x0 = A[(size_t)grow * lda + k + 0];
                        if (k + 1 < K) x1 = A[(size_t)grow * lda + k + 1];
                        if (k + 2 < K) x2 = A[(size_t)grow * lda + k + 2];
                        if (k + 3 < K) x3 = A[(size_t)grow * lda + k + 3];
                    }
                }
                s4 = (bf16x4){ (short)f2bf(x0), (short)f2bf(x1), (short)f2bf(x2), (short)f2bf(x3) };
            }
            *reinterpret_cast<bf16x4*>(As + row * LDP + tc) = s4;
        }
        // stage Wt tile (bf16), 64 out-cols x 64 k
        #pragma unroll
        for (int p = 0; p < 4; ++p) {
            int n = p * 16 + tr;
            int k = k0 + tc;
            bf16x4 s4;
            if (k + 4 <= K) {
                s4 = *reinterpret_cast<const bf16x4*>(Wt + (size_t)(bn + n) * K + k);
            } else {
                short e0 = 0, e1 = 0, e2 = 0, e3 = 0;
                if (k + 0 < K) e0 = (short)Wt[(size_t)(bn + n) * K + k + 0];
                if (k + 1 < K) e1 = (short)Wt[(size_t)(bn + n) * K + k + 1];
                if (k + 2 < K) e2 = (short)Wt[(size_t)(bn + n) * K + k + 2];
                if (k + 3 < K) e3 = (short)Wt[(size_t)(bn + n) * K + k + 3];
                s4 = (bf16x4){ e0, e1, e2, e3 };
            }
            *reinterpret_cast<bf16x4*>(Bs + n * LDP + tc) = s4;
        }
        __syncthreads();
        #pragma unroll
        for (int ks = 0; ks < 2; ++ks) {
            int kk = ks * 32 + fg * 8;
            bf16x8 a0 = *reinterpret_cast<const bf16x8*>(As + (wv * 32 + fr) * LDP + kk);
            bf16x8 a1 = *reinterpret_cast<const bf16x8*>(As + (wv * 32 + 16 + fr) * LDP + kk);
            #pragma unroll
            for (int nj = 0; nj < 4; ++nj) {
                bf16x8 b = *reinterpret_cast<const bf16x8*>(Bs + (nj * 16 + fr) * LDP + kk);
                acc[0][nj] = __builtin_amdgcn_mfma_f32_16x16x32_bf16(a0, b, acc[0][nj], 0, 0, 0);
                acc[1][nj] = __builtin_amdgcn_mfma_f32_16x16x32_bf16(a1, b, acc[1][nj], 0, 0, 0);
            }
        }
        __syncthreads();
    }
    // epilogue: C/D layout col=lane&15, row=(lane>>4)*4+reg
    #pragma unroll
    for (int mi = 0; mi < 2; ++mi) {
        int row0 = bm + wv * 32 + mi * 16 + fg * 4;
        #pragma unroll
        for (int nj = 0; nj < 4; ++nj) {
            int col = bn + nj * 16 + fr;
            float bv = bias[col];
            #pragma unroll
            for (int r = 0; r < 4; ++r) {
                int gr = row0 + r;
                if (gr >= M) continue;
                float val = acc[mi][nj][r] + bv;
                if (relu) val = fmaxf(val, 0.f);
                C[(size_t)gr * ldc + col] = f2bf(val);
            }
        }
    }
}

// ---------------- CSR build (group edges by dst) ----------------
__global__ void k_hist(const int* __restrict__ dstv, int* __restrict__ deg, int E) {
    int e = blockIdx.x * 256 + threadIdx.x;
    if (e < E) atomicAdd(&deg[dstv[e]], 1);
}

__global__ void k_scan1(const int* __restrict__ deg, int* __restrict__ ex,
                        int* __restrict__ bsum, int n) {
    __shared__ int tmp[256];
    int i = blockIdx.x * 256 + threadIdx.x;
    int v = (i < n) ? deg[i] : 0;
    tmp[threadIdx.x] = v;
    __syncthreads();
    for (int off = 1; off < 256; off <<= 1) {
        int t = (threadIdx.x >= off) ? tmp[threadIdx.x - off] : 0;
        __syncthreads();
        tmp[threadIdx.x] += t;
        __syncthreads();
    }
    if (i < n) ex[i] = tmp[threadIdx.x] - v;
    if (threadIdx.x == 255) bsum[blockIdx.x] = tmp[255];
}

__global__ void k_scan2(int* __restrict__ bsum, int nb) {
    __shared__ int tmp[256];
    int v = (threadIdx.x < nb) ? bsum[threadIdx.x] : 0;
    tmp[threadIdx.x] = v;
    __syncthreads();
    for (int off = 1; off < 256; off <<= 1) {
        int t = (threadIdx.x >= off) ? tmp[threadIdx.x - off] : 0;
        __syncthreads();
        tmp[threadIdx.x] += t;
        __syncthreads();
    }
    if (threadIdx.x < nb) bsum[threadIdx.x] = tmp[threadIdx.x] - v;
}

__global__ void k_scan3(int* __restrict__ rp, const int* __restrict__ bsum,
                        int* __restrict__ cursor, int n, int E) {
    int i = blockIdx.x * 256 + threadIdx.x;
    if (i < n) {
        int r = rp[i] + bsum[blockIdx.x];
        rp[i] = r;
        cursor[i] = r;
    }
    if (i == 0) rp[n] = E;
}

__global__ void k_fill(const int* __restrict__ src, const int* __restrict__ dstv,
                       int* __restrict__ cursor, int* __restrict__ esrc, int E) {
    int e = blockIdx.x * 256 + threadIdx.x;
    if (e >= E) return;
    int d = dstv[e];
    int p = atomicAdd(&cursor[d], 1);
    esrc[p] = src[e];
}

// ---------------- attention, heads=2, d_head=64; qkvs row = q|k|v|s (128 each, bf16) ----------------
// Lane l owns elems {2l, 2l+1}; lanes 0-31 = head0, 32-63 = head1.
__global__ __launch_bounds__(256) void attn_h2(
    const unsigned short* __restrict__ qkvs,
    const int* __restrict__ rowptr, const int* __restrict__ esrc,
    unsigned short* __restrict__ outp, int N)
{
    int wid = (blockIdx.x * blockDim.x + threadIdx.x) >> 6;
    int l = threadIdx.x & 63;
    if (wid >= N) return;
    const unsigned short* bi = qkvs + (size_t)wid * 512;
    ushort2 qv = *reinterpret_cast<const ushort2*>(bi + 2 * l);
    float q0 = bf2f(qv.x) * 0.125f, q1 = bf2f(qv.y) * 0.125f;
    float m = -1e30f, s = 0.f, a0 = 0.f, a1 = 0.f;
    const int beg = rowptr[wid], end = rowptr[wid + 1];
    int e = beg;
    for (; e + 1 < end; e += 2) {
        int j0 = esrc[e], j1 = esrc[e + 1];
        const unsigned short* b0 = qkvs + (size_t)j0 * 512;
        const unsigned short* b1 = qkvs + (size_t)j1 * 512;
        ushort2 ka = *reinterpret_cast<const ushort2*>(b0 + 128 + 2 * l);
        ushort2 va = *reinterpret_cast<const ushort2*>(b0 + 256 + 2 * l);
        ushort2 kc = *reinterpret_cast<const ushort2*>(b1 + 128 + 2 * l);
        ushort2 vc = *reinterpret_cast<const ushort2*>(b1 + 256 + 2 * l);
        float p0 = q0 * bf2f(ka.x) + q1 * bf2f(ka.y);
        float p1 = q0 * bf2f(kc.x) + q1 * bf2f(kc.y);
        #pragma unroll
        for (int off = 16; off > 0; off >>= 1) {
            p0 += __shfl_xor(p0, off, 64);
            p1 += __shfl_xor(p1, off, 64);
        }
        float nm = fmaxf(m, p0);
        float f  = __expf(m - nm);
        float w  = __expf(p0 - nm);
        s = s * f + w; a0 = a0 * f + w * bf2f(va.x); a1 = a1 * f + w * bf2f(va.y); m = nm;
        nm = fmaxf(m, p1);
        f  = __expf(m - nm);
        w  = __expf(p1 - nm);
        s = s * f + w; a0 = a0 * f + w * bf2f(vc.x); a1 = a1 * f + w * bf2f(vc.y); m = nm;
    }
    if (e < end) {
        int j0 = esrc[e];
        const unsigned short* b0 = qkvs + (size_t)j0 * 512;
        ushort2 ka = *reinterpret_cast<const ushort2*>(b0 + 128 + 2 * l);
        ushort2 va = *reinterpret_cast<const ushort2*>(b0 + 256 + 2 * l);
        float p0 = q0 * bf2f(ka.x) + q1 * bf2f(ka.y);
        #pragma unroll
        for (int off = 16; off > 0; off >>= 1) p0 += __shfl_xor(p0, off, 64);
        float nm = fmaxf(m, p0);
        float f  = __expf(m - nm);
        float w  = __expf(p0 - nm);
        s = s * f + w; a0 = a0 * f + w * bf2f(va.x); a1 = a1 * f + w * bf2f(va.y); m = nm;
    }
    float inv = 1.f / (s + 1e-16f);
    ushort2 sv = *reinterpret_cast<const ushort2*>(bi + 384 + 2 * l);
    float r0 = fmaxf(a0 * inv + bf2f(sv.x), 0.f);   // relu fused (post-conv1)
    float r1 = fmaxf(a1 * inv + bf2f(sv.y), 0.f);
    ushort2 o; o.x = f2bf(r0); o.y = f2bf(r1);
    *reinterpret_cast<ushort2*>(outp + (size_t)wid * 128 + 2 * l) = o;
}

// ---------------- attention, heads=1, d=64; qkvs row = q|k|v|s (64 each, bf16) ----------------
// 2 edges in flight (one per 32-lane half); output f32.
__global__ __launch_bounds__(256) void attn_h1(
    const unsigned short* __restrict__ qkvs,
    const int* __restrict__ rowptr, const int* __restrict__ esrc,
    float* __restrict__ outp, int N)
{
    int wid = (blockIdx.x * blockDim.x + threadIdx.x) >> 6;
    int l = threadIdx.x & 63;
    if (wid >= N) return;
    int li = l & 31, h = l >> 5;
    const unsigned short* bi = qkvs + (size_t)wid * 256;
    ushort2 qv = *reinterpret_cast<const ushort2*>(bi + 2 * li);
    float q0 = bf2f(qv.x) * 0.125f, q1 = bf2f(qv.y) * 0.125f;
    float m = -1e30f, s = 0.f, a0 = 0.f, a1 = 0.f;
    const int beg = rowptr[wid], end = rowptr[wid + 1];
    int deg = end - beg;
    int iters = (deg + 1) >> 1;
    for (int it = 0; it < iters; ++it) {
        int e = beg + 2 * it + h;
        bool valid = e < end;
        int j = valid ? esrc[e] : esrc[beg];
        const unsigned short* bj = qkvs + (size_t)j * 256;
        ushort2 kv = *reinterpret_cast<const ushort2*>(bj + 64 + 2 * li);
        ushort2 vv = *reinterpret_cast<const ushort2*>(bj + 128 + 2 * li);
        float p = q0 * bf2f(kv.x) + q1 * bf2f(kv.y);
        #pragma unroll
        for (int off = 16; off > 0; off >>= 1) p += __shfl_xor(p, off, 64);
        float nm = valid ? fmaxf(m, p) : m;
        float f  = __expf(m - nm);
        float w  = valid ? __expf(p - nm) : 0.f;
        s = s * f + w; a0 = a0 * f + w * bf2f(vv.x); a1 = a1 * f + w * bf2f(vv.y); m = nm;
    }
    // merge the two halves' online-softmax states
    float om  = __shfl_xor(m, 32, 64);
    float M_  = fmaxf(m, om);
    float fm  = __expf(m - M_);
    float ofm = __expf(om - M_);
    float os  = __shfl_xor(s, 32, 64);
    float oa0 = __shfl_xor(a0, 32, 64);
    float oa1 = __shfl_xor(a1, 32, 64);
    float St = s * fm + os * ofm;
    float A0 = a0 * fm + oa0 * ofm;
    float A1 = a1 * fm + oa1 * ofm;
    if (h == 0) {
        float inv = 1.f / (St + 1e-16f);
        float r0 = A0 * inv + bf2f(bi[192 + 2 * li]);
        float r1 = A1 * inv + bf2f(bi[192 + 2 * li + 1]);
        *reinterpret_cast<float2*>(outp + (size_t)wid * 64 + 2 * li) = make_float2(r0, r1);
    }
}

// ---------------- global mean pool (batch is sorted) ----------------
__device__ __forceinline__ int lbound(const int* __restrict__ a, int n, int key) {
    int lo = 0, hi = n;
    while (lo < hi) {
        int mid = (lo + hi) >> 1;
        if (a[mid] < key) lo = mid + 1; else hi = mid;
    }
    return lo;
}

__global__ void pool_mean(const float* __restrict__ h, const int* __restrict__ batch,
                          float* __restrict__ pooled) {
    int g = blockIdx.x;
    int l = threadIdx.x;
    int lo = lbound(batch, NNODES, g);
    int hi = lbound(batch, NNODES, g + 1);
    float s0 = 0.f, s1 = 0.f, s2 = 0.f, s3 = 0.f;
    int i = lo;
    for (; i + 3 < hi; i += 4) {
        s0 += h[(size_t)(i + 0) * 64 + l];
        s1 += h[(size_t)(i + 1) * 64 + l];
        s2 += h[(size_t)(i + 2) * 64 + l];
        s3 += h[(size_t)(i + 3) * 64 + l];
    }
    for (; i < hi; ++i) s0 += h[(size_t)i * 64 + l];
    float cnt = (float)((hi - lo) > 1 ? (hi - lo) : 1);
    pooled[g * 64 + l] = (s0 + s1 + s2 + s3) / cnt;
}

// ---------------- head MLP ----------------
__global__ void head_mlp(const float* __restrict__ pooled,
                         const float* __restrict__ l1W, const float* __restrict__ l1b,
                         const float* __restrict__ l2W, const float* __restrict__ l2b,
                         float* __restrict__ out) {
    int g = blockIdx.x;
    int l = threadIdx.x & 63;
    float p = pooled[g * 64 + l];
    float hsum = l1b[l];
    #pragma unroll
    for (int kk = 0; kk < 64; ++kk) {
        float pk = __shfl(p, kk, 64);
        hsum += pk * l1W[kk * 64 + l];
    }
    float h = fmaxf(hsum, 0.f);
    float o0 = h * l2W[l * 2 + 0];
    float o1 = h * l2W[l * 2 + 1];
    #pragma unroll
    for (int off = 32; off > 0; off >>= 1) {
        o0 += __shfl_xor(o0, off, 64);
        o1 += __shfl_xor(o1, off, 64);
    }
    if (l == 0) {
        out[g * 2 + 0] = o0 + l2b[0];
        out[g * 2 + 1] = o1 + l2b[1];
    }
}

// ---------------- host launch ----------------
extern "C" void kernel_launch(void* const* d_in, const int* in_sizes, int n_in,
                              void* d_out, int out_size, void* d_ws, size_t ws_size,
                              hipStream_t stream) {
    const float* x      = (const float*)d_in[0];
    const int*   ei     = (const int*)d_in[1];
    const int*   batch  = (const int*)d_in[2];
    const float* syn_W  = (const float*)d_in[3];  const float* syn_b = (const float*)d_in[4];
    const float* ant_W  = (const float*)d_in[5];  const float* ant_b = (const float*)d_in[6];
    const float* fus_W  = (const float*)d_in[7];  const float* fus_b = (const float*)d_in[8];
    const float* c1_Wq  = (const float*)d_in[9];  const float* c1_bq = (const float*)d_in[10];
    const float* c1_Wk  = (const float*)d_in[11]; const float* c1_bk = (const float*)d_in[12];
    const float* c1_Wv  = (const float*)d_in[13]; const float* c1_bv = (const float*)d_in[14];
    const float* c1_Ws  = (const float*)d_in[15]; const float* c1_bs = (const float*)d_in[16];
    const float* c2_Wq  = (const float*)d_in[17]; const float* c2_bq = (const float*)d_in[18];
    const float* c2_Wk  = (const float*)d_in[19]; const float* c2_bk = (const float*)d_in[20];
    const float* c2_Wv  = (const float*)d_in[21]; const float* c2_bv = (const float*)d_in[22];
    const float* c2_Ws  = (const float*)d_in[23]; const float* c2_bs = (const float*)d_in[24];
    const float* l1_W   = (const float*)d_in[25]; const float* l1_b  = (const float*)d_in[26];
    const float* l2_W   = (const float*)d_in[27]; const float* l2_b  = (const float*)d_in[28];
    const int* src = ei;
    const int* dst = ei + NEDGES;
    float* out = (float*)d_out;

    char* ws = (char*)d_ws;
    size_t off = 0;
    auto alloc = [&](size_t bytes) -> char* {
        char* p = ws + off;
        off += (bytes + 255) & ~((size_t)255);
        return p;
    };

    unsigned short* xfin  = (unsigned short*)alloc((size_t)NNODES * 128 * 2);  // enc out; later H (conv1 out)
    unsigned short* xfus  = (unsigned short*)alloc((size_t)NNODES * 128 * 2);  // fused; later H2 (f32, 64-wide: same bytes)
    unsigned short* qkvs1 = (unsigned short*)alloc((size_t)NNODES * 512 * 2);
    unsigned short* qkvs2 = (unsigned short*)alloc((size_t)NNODES * 256 * 2);
    unsigned short* enc_t = (unsigned short*)alloc((size_t)128 * 300 * 2);
    unsigned short* fus_t = (unsigned short*)alloc((size_t)128 * 128 * 2);
    unsigned short* c1w_t = (unsigned short*)alloc((size_t)512 * 128 * 2);
    unsigned short* c2w_t = (unsigned short*)alloc((size_t)256 * 128 * 2);
    float* enc_b = (float*)alloc(128 * 4);
    float* c1_b  = (float*)alloc(512 * 4);
    float* c2_b  = (float*)alloc(256 * 4);
    int*   deg    = (int*)alloc((NNODES + 1) * 4);
    int*   cursor = (int*)alloc((NNODES + 1) * 4);
    int*   rowptr = (int*)alloc((NNODES + 1) * 4);
    int*   bsum   = (int*)alloc(256 * 4);
    int*   esrc   = (int*)alloc((size_t)NEDGES * 4);
    float* pooled = (float*)alloc((size_t)NGRAPH * 64 * 4);

    const int MB = (NNODES + BM - 1) / BM;   // 391
    const int EB = (NEDGES + 255) / 256;
    const int NB = (NNODES + 255) / 256;
    dim3 t256(256);

    // --- weight transposes (slices of fused buffers) ---
    WTArgs wa;
    wa.w[0] = syn_W;  wa.o[0] = enc_t;             wa.K[0] = 300; wa.N[0] = 64;
    wa.w[1] = ant_W;  wa.o[1] = enc_t + 64 * 300;  wa.K[1] = 300; wa.N[1] = 64;
    wa.w[2] = fus_W;  wa.o[2] = fus_t;             wa.K[2] = 128; wa.N[2] = 128;
    wa.w[3] = c1_Wq;  wa.o[3] = c1w_t + 0 * 128 * 128; wa.K[3] = 128; wa.N[3] = 128;
    wa.w[4] = c1_Wk;  wa.o[4] = c1w_t + 1 * 128 * 128; wa.K[4] = 128; wa.N[4] = 128;
    wa.w[5] = c1_Wv;  wa.o[5] = c1w_t + 2 * 128 * 128; wa.K[5] = 128; wa.N[5] = 128;
    wa.w[6] = c1_Ws;  wa.o[6] = c1w_t + 3 * 128 * 128; wa.K[6] = 128; wa.N[6] = 128;
    wa.w[7] = c2_Wq;  wa.o[7] = c2w_t + 0 * 64 * 128;  wa.K[7] = 128; wa.N[7] = 64;
    wa.w[8] = c2_Wk;  wa.o[8] = c2w_t + 1 * 64 * 128;  wa.K[8] = 128; wa.N[8] = 64;
    wa.w[9] = c2_Wv;  wa.o[9] = c2w_t + 2 * 64 * 128;  wa.K[9] = 128; wa.N[9] = 64;
    wa.w[10] = c2_Ws; wa.o[10] = c2w_t + 3 * 64 * 128; wa.K[10] = 128; wa.N[10] = 64;
    k_wt<<<dim3(75, 11), t256, 0, stream>>>(wa);

    BiasArgs ba;
    ba.syn_b = syn_b; ba.ant_b = ant_b;
    ba.c1q = c1_bq; ba.c1k = c1_bk; ba.c1v = c1_bv; ba.c1s = c1_bs;
    ba.c2q = c2_bq; ba.c2k = c2_bk; ba.c2v = c2_bv; ba.c2s = c2_bs;
    ba.enc_b = enc_b; ba.c1_b = c1_b; ba.c2_b = c2_b;
    k_bias<<<1, 1024, 0, stream>>>(ba);

    // --- CSR build ---
    hipMemsetAsync(deg, 0, (NNODES + 1) * sizeof(int), stream);
    k_hist<<<EB, t256, 0, stream>>>(dst, deg, NEDGES);
    k_scan1<<<NB, t256, 0, stream>>>(deg, rowptr, bsum, NNODES);
    k_scan2<<<1, t256, 0, stream>>>(bsum, NB);
    k_scan3<<<NB, t256, 0, stream>>>(rowptr, bsum, cursor, NNODES, NEDGES);
    k_fill<<<EB, t256, 0, stream>>>(src, dst, cursor, esrc, NEDGES);

    // --- encoders (fused syn||ant) + relu ---
    gemm_mfma<false><<<dim3(MB, 2), t256, 0, stream>>>(x, INC, NNODES, INC, enc_t, enc_b, xfin, 128, 1);
    // --- fusion ---
    gemm_mfma<true><<<dim3(MB, 2), t256, 0, stream>>>(xfin, 128, NNODES, 128, fus_t, fus_b, xfus, 128, 0);
    // --- conv1 q|k|v|s fused (N=512) ---
    gemm_mfma<true><<<dim3(MB, 8), t256, 0, stream>>>(xfus, 128, NNODES, 128, c1w_t, c1_b, qkvs1, 512, 0);
    // --- conv1 attention + relu -> H (reuse xfin, bf16) ---
    unsigned short* H = xfin;
    attn_h2<<<(NNODES * 64 + 255) / 256, t256, 0, stream>>>(qkvs1, rowptr, esrc, H, NNODES);
    // --- conv2 q|k|v|s fused (N=256) ---
    gemm_mfma<true><<<dim3(MB, 4), t256, 0, stream>>>(H, 128, NNODES, 128, c2w_t, c2_b, qkvs2, 256, 0);
    // --- conv2 attention -> H2 (f32, reuse xfus bytes) ---
    float* H2 = (float*)xfus;
    attn_h1<<<(NNODES * 64 + 255) / 256, t256, 0, stream>>>(qkvs2, rowptr, esrc, H2, NNODES);

    // --- pool + head ---
    pool_mean<<<NGRAPH, 64, 0, stream>>>(H2, batch, pooled);
    head_mlp<<<NGRAPH, 64, 0, stream>>>(pooled, l1_W, l1_b, l2_W, l2_b, out);
}

// Round 4
// 347.027 us; speedup vs baseline: 2.3408x; 1.1016x over previous
//
#include <hip/hip_runtime.h>
#include <math.h>

#define NNODES 50000
#define NEDGES 800000
#define INC    300
#define NGRAPH 256

typedef __attribute__((ext_vector_type(8))) short bf16x8;
typedef __attribute__((ext_vector_type(4))) short bf16x4;
typedef __attribute__((ext_vector_type(4))) float f32x4;

__device__ __forceinline__ unsigned short f2bf(float f) {
    unsigned u = __float_as_uint(f);
    u += 0x7fffu + ((u >> 16) & 1u);
    return (unsigned short)(u >> 16);
}
__device__ __forceinline__ float bf2f(unsigned short h) {
    return __uint_as_float(((unsigned)h) << 16);
}

// ---------------- weight transpose+cast: W[K][N] f32 -> Wt[N][K] bf16 ----------------
struct WTArgs {
    const float* w[11];
    unsigned short* o[11];
    int K[11];
    int N[11];
};

__global__ void k_wt(WTArgs args) {
    int which = blockIdx.y;
    int i = blockIdx.x * 256 + threadIdx.x;
    int K = args.K[which], N = args.N[which];
    if (i >= K * N) return;
    int k = i / N, n = i - k * N;
    args.o[which][(size_t)n * K + k] = f2bf(args.w[which][i]);
}

// ---------------- bias concat ----------------
struct BiasArgs {
    const float* syn_b; const float* ant_b;
    const float* c1q; const float* c1k; const float* c1v; const float* c1s;
    const float* c2q; const float* c2k; const float* c2v; const float* c2s;
    float* enc_b;   // [128]
    float* c1_b;    // [512]
    float* c2_b;    // [256]
};

__global__ void k_bias(BiasArgs a) {
    int t = threadIdx.x;  // 1024
    if (t < 512) {
        int s = t >> 7, r = t & 127;
        const float* p = (s == 0) ? a.c1q : (s == 1) ? a.c1k : (s == 2) ? a.c1v : a.c1s;
        a.c1_b[t] = p[r];
    } else if (t < 768) {
        int u = t - 512;
        int s = u >> 6, r = u & 63;
        const float* p = (s == 0) ? a.c2q : (s == 1) ? a.c2k : (s == 2) ? a.c2v : a.c2s;
        a.c2_b[u] = p[r];
    } else if (t < 896) {
        int u = t - 768;
        a.enc_b[u] = (u < 64) ? a.syn_b[u] : a.ant_b[u - 64];
    }
}

// ---------------- MFMA GEMM: C[M,N] = act(A[M,K] @ Wt^T + bias), C in bf16 ----------------
#define BM 128
#define BN 64
#define BK 64
#define LDP 72   // padded LDS leading dim (bf16 elems)

template<bool ABF16>
__global__ __launch_bounds__(256) void gemm_mfma(
    const void* __restrict__ Av, int lda, int M, int K,
    const unsigned short* __restrict__ Wt,
    const float* __restrict__ bias,
    unsigned short* __restrict__ C, int ldc, int relu)
{
    __shared__ __align__(16) short As[BM * LDP];
    __shared__ __align__(16) short Bs[BN * LDP];
    const int tid = threadIdx.x;
    const int bm = blockIdx.x * BM;
    const int bn = blockIdx.y * BN;
    const int tr = tid >> 4;          // 0..15
    const int tc = (tid & 15) * 4;    // 0..60
    const int l  = tid & 63;
    const int wv = tid >> 6;          // wave 0..3
    const int fr = l & 15;
    const int fg = l >> 4;            // 0..3

    f32x4 acc[2][4];
    #pragma unroll
    for (int i = 0; i < 2; ++i)
        #pragma unroll
        for (int j = 0; j < 4; ++j) acc[i][j] = (f32x4){0.f, 0.f, 0.f, 0.f};

    for (int k0 = 0; k0 < K; k0 += BK) {
        #pragma unroll
        for (int p = 0; p < 8; ++p) {
            int row = p * 16 + tr;
            int grow = bm + row;
            int k = k0 + tc;
            bf16x4 s4;
            if constexpr (ABF16) {
                const unsigned short* A = (const unsigned short*)Av;
                if (grow < M && k + 4 <= K) {
                    s4 = *reinterpret_cast<const bf16x4*>(A + (size_t)grow * lda + k);
                } else {
                    short e0 = 0, e1 = 0, e2 = 0, e3 = 0;
                    if (grow < M) {
                        if (k + 0 < K) e0 = (short)A[(size_t)grow * lda + k + 0];
                        if (k + 1 < K) e1 = (short)A[(size_t)grow * lda + k + 1];
                        if (k + 2 < K) e2 = (short)A[(size_t)grow * lda + k + 2];
                        if (k + 3 < K) e3 = (short)A[(size_t)grow * lda + k + 3];
                    }
                    s4 = (bf16x4){ e0, e1, e2, e3 };
                }
            } else {
                const float* A = (const float*)Av;
                float x0 = 0.f, x1 = 0.f, x2 = 0.f, x3 = 0.f;
                if (grow < M) {
                    if (k + 4 <= K) {
                        float4 a4 = *reinterpret_cast<const float4*>(A + (size_t)grow * lda + k);
                        x0 = a4.x; x1 = a4.y; x2 = a4.z; x3 = a4.w;
                    } else {
                        if (k + 0 < K) x0 = A[(size_t)grow * lda + k + 0];
                        if (k + 1 < K) x1 = A[(size_t)grow * lda + k + 1];
                        if (k + 2 < K) x2 = A[(size_t)grow * lda + k + 2];
                        if (k + 3 < K) x3 = A[(size_t)grow * lda + k + 3];
                    }
                }
                s4 = (bf16x4){ (short)f2bf(x0), (short)f2bf(x1), (short)f2bf(x2), (short)f2bf(x3) };
            }
            *reinterpret_cast<bf16x4*>(As + row * LDP + tc) = s4;
        }
        #pragma unroll
        for (int p = 0; p < 4; ++p) {
            int n = p * 16 + tr;
            int k = k0 + tc;
            bf16x4 s4;
            if (k + 4 <= K) {
                s4 = *reinterpret_cast<const bf16x4*>(Wt + (size_t)(bn + n) * K + k);
            } else {
                short e0 = 0, e1 = 0, e2 = 0, e3 = 0;
                if (k + 0 < K) e0 = (short)Wt[(size_t)(bn + n) * K + k + 0];
                if (k + 1 < K) e1 = (short)Wt[(size_t)(bn + n) * K + k + 1];
                if (k + 2 < K) e2 = (short)Wt[(size_t)(bn + n) * K + k + 2];
                if (k + 3 < K) e3 = (short)Wt[(size_t)(bn + n) * K + k + 3];
                s4 = (bf16x4){ e0, e1, e2, e3 };
            }
            *reinterpret_cast<bf16x4*>(Bs + n * LDP + tc) = s4;
        }
        __syncthreads();
        #pragma unroll
        for (int ks = 0; ks < 2; ++ks) {
            int kk = ks * 32 + fg * 8;
            bf16x8 a0 = *reinterpret_cast<const bf16x8*>(As + (wv * 32 + fr) * LDP + kk);
            bf16x8 a1 = *reinterpret_cast<const bf16x8*>(As + (wv * 32 + 16 + fr) * LDP + kk);
            #pragma unroll
            for (int nj = 0; nj < 4; ++nj) {
                bf16x8 b = *reinterpret_cast<const bf16x8*>(Bs + (nj * 16 + fr) * LDP + kk);
                acc[0][nj] = __builtin_amdgcn_mfma_f32_16x16x32_bf16(a0, b, acc[0][nj], 0, 0, 0);
                acc[1][nj] = __builtin_amdgcn_mfma_f32_16x16x32_bf16(a1, b, acc[1][nj], 0, 0, 0);
            }
        }
        __syncthreads();
    }
    #pragma unroll
    for (int mi = 0; mi < 2; ++mi) {
        int row0 = bm + wv * 32 + mi * 16 + fg * 4;
        #pragma unroll
        for (int nj = 0; nj < 4; ++nj) {
            int col = bn + nj * 16 + fr;
            float bv = bias[col];
            #pragma unroll
            for (int r = 0; r < 4; ++r) {
                int gr = row0 + r;
                if (gr >= M) continue;
                float val = acc[mi][nj][r] + bv;
                if (relu) val = fmaxf(val, 0.f);
                C[(size_t)gr * ldc + col] = f2bf(val);
            }
        }
    }
}

// ---------------- CSR build (group edges by dst) ----------------
__global__ void k_hist(const int* __restrict__ dstv, int* __restrict__ deg, int E) {
    int e = blockIdx.x * 256 + threadIdx.x;
    if (e < E) atomicAdd(&deg[dstv[e]], 1);
}

__global__ void k_scan1(const int* __restrict__ deg, int* __restrict__ ex,
                        int* __restrict__ bsum, int n) {
    __shared__ int tmp[256];
    int i = blockIdx.x * 256 + threadIdx.x;
    int v = (i < n) ? deg[i] : 0;
    tmp[threadIdx.x] = v;
    __syncthreads();
    for (int off = 1; off < 256; off <<= 1) {
        int t = (threadIdx.x >= off) ? tmp[threadIdx.x - off] : 0;
        __syncthreads();
        tmp[threadIdx.x] += t;
        __syncthreads();
    }
    if (i < n) ex[i] = tmp[threadIdx.x] - v;
    if (threadIdx.x == 255) bsum[blockIdx.x] = tmp[255];
}

__global__ void k_scan2(int* __restrict__ bsum, int nb) {
    __shared__ int tmp[256];
    int v = (threadIdx.x < nb) ? bsum[threadIdx.x] : 0;
    tmp[threadIdx.x] = v;
    __syncthreads();
    for (int off = 1; off < 256; off <<= 1) {
        int t = (threadIdx.x >= off) ? tmp[threadIdx.x - off] : 0;
        __syncthreads();
        tmp[threadIdx.x] += t;
        __syncthreads();
    }
    if (threadIdx.x < nb) bsum[threadIdx.x] = tmp[threadIdx.x] - v;
}

__global__ void k_scan3(int* __restrict__ rp, const int* __restrict__ bsum,
                        int* __restrict__ cursor, int n, int E) {
    int i = blockIdx.x * 256 + threadIdx.x;
    if (i < n) {
        int r = rp[i] + bsum[blockIdx.x];
        rp[i] = r;
        cursor[i] = r;
    }
    if (i == 0) rp[n] = E;
}

__global__ void k_fill(const int* __restrict__ src, const int* __restrict__ dstv,
                       int* __restrict__ cursor, int* __restrict__ esrc, int E) {
    int e = blockIdx.x * 256 + threadIdx.x;
    if (e >= E) return;
    int d = dstv[e];
    int p = atomicAdd(&cursor[d], 1);
    esrc[p] = src[e];
}

// ---------------- attention, heads=2, d_head=64; qkvs row = q|k|v|s (128 each, bf16) ----------------
// Lane layout: sl = l&15 owns elems 8*sl..8*sl+7 (head = sl>>3); g = l>>4 = edge stream 0..3.
__global__ __launch_bounds__(256) void attn_h2(
    const unsigned short* __restrict__ qkvs,
    const int* __restrict__ rowptr, const int* __restrict__ esrc,
    unsigned short* __restrict__ outp, int N)
{
    int wid = (blockIdx.x * blockDim.x + threadIdx.x) >> 6;
    int l = threadIdx.x & 63;
    if (wid >= N) return;
    const int sl = l & 15;
    const int g  = l >> 4;
    const unsigned short* bi = qkvs + (size_t)wid * 512;
    float q[8];
    {
        bf16x8 qv = *reinterpret_cast<const bf16x8*>(bi + 8 * sl);
        #pragma unroll
        for (int i = 0; i < 8; ++i) q[i] = bf2f((unsigned short)qv[i]) * 0.125f;
    }
    float m = -1e30f, s = 0.f;
    float acc[8] = {0.f, 0.f, 0.f, 0.f, 0.f, 0.f, 0.f, 0.f};
    const int beg = rowptr[wid], end = rowptr[wid + 1];
    const int iters = (end - beg + 3) >> 2;
    for (int it = 0; it < iters; ++it) {
        int e = beg + it * 4 + g;
        bool valid = e < end;
        int j = valid ? esrc[e] : 0;
        const unsigned short* bj = qkvs + (size_t)j * 512;
        bf16x8 kv = *reinterpret_cast<const bf16x8*>(bj + 128 + 8 * sl);
        bf16x8 vv = *reinterpret_cast<const bf16x8*>(bj + 256 + 8 * sl);
        float p = 0.f;
        #pragma unroll
        for (int i = 0; i < 8; ++i) p += q[i] * bf2f((unsigned short)kv[i]);
        // reduce over the 8 lanes of this head-subgroup
        p += __shfl_xor(p, 1, 64);
        p += __shfl_xor(p, 2, 64);
        p += __shfl_xor(p, 4, 64);
        float nm = valid ? fmaxf(m, p) : m;
        float f  = __expf(m - nm);
        float w  = valid ? __expf(p - nm) : 0.f;
        s = s * f + w;
        #pragma unroll
        for (int i = 0; i < 8; ++i) acc[i] = acc[i] * f + w * bf2f((unsigned short)vv[i]);
        m = nm;
    }
    // merge the 4 edge streams (lane-groups xor 16, xor 32)
    #pragma unroll
    for (int mask = 16; mask <= 32; mask <<= 1) {
        float om = __shfl_xor(m, mask, 64);
        float os = __shfl_xor(s, mask, 64);
        float oa[8];
        #pragma unroll
        for (int i = 0; i < 8; ++i) oa[i] = __shfl_xor(acc[i], mask, 64);
        float M_ = fmaxf(m, om);
        float f  = __expf(m - M_);
        float of = __expf(om - M_);
        s = s * f + os * of;
        #pragma unroll
        for (int i = 0; i < 8; ++i) acc[i] = acc[i] * f + oa[i] * of;
        m = M_;
    }
    if (g == 0) {
        float inv = 1.f / (s + 1e-16f);
        bf16x8 sv = *reinterpret_cast<const bf16x8*>(bi + 384 + 8 * sl);
        bf16x8 o;
        #pragma unroll
        for (int i = 0; i < 8; ++i) {
            float r = fmaxf(acc[i] * inv + bf2f((unsigned short)sv[i]), 0.f);  // relu fused
            o[i] = (short)f2bf(r);
        }
        *reinterpret_cast<bf16x8*>(outp + (size_t)wid * 128 + 8 * sl) = o;
    }
}

// ---------------- attention, heads=1, d=64; qkvs row = q|k|v|s (64 each, bf16) ----------------
// Lane layout: sl = l&7 owns elems 8*sl..8*sl+7; g = l>>3 = edge stream 0..7. Output f32.
__global__ __launch_bounds__(256) void attn_h1(
    const unsigned short* __restrict__ qkvs,
    const int* __restrict__ rowptr, const int* __restrict__ esrc,
    float* __restrict__ outp, int N)
{
    int wid = (blockIdx.x * blockDim.x + threadIdx.x) >> 6;
    int l = threadIdx.x & 63;
    if (wid >= N) return;
    const int sl = l & 7;
    const int g  = l >> 3;
    const unsigned short* bi = qkvs + (size_t)wid * 256;
    float q[8];
    {
        bf16x8 qv = *reinterpret_cast<const bf16x8*>(bi + 8 * sl);
        #pragma unroll
        for (int i = 0; i < 8; ++i) q[i] = bf2f((unsigned short)qv[i]) * 0.125f;
    }
    float m = -1e30f, s = 0.f;
    float acc[8] = {0.f, 0.f, 0.f, 0.f, 0.f, 0.f, 0.f, 0.f};
    const int beg = rowptr[wid], end = rowptr[wid + 1];
    const int iters = (end - beg + 7) >> 3;
    for (int it = 0; it < iters; ++it) {
        int e = beg + it * 8 + g;
        bool valid = e < end;
        int j = valid ? esrc[e] : 0;
        const unsigned short* bj = qkvs + (size_t)j * 256;
        bf16x8 kv = *reinterpret_cast<const bf16x8*>(bj + 64 + 8 * sl);
        bf16x8 vv = *reinterpret_cast<const bf16x8*>(bj + 128 + 8 * sl);
        float p = 0.f;
        #pragma unroll
        for (int i = 0; i < 8; ++i) p += q[i] * bf2f((unsigned short)kv[i]);
        p += __shfl_xor(p, 1, 64);
        p += __shfl_xor(p, 2, 64);
        p += __shfl_xor(p, 4, 64);
        float nm = valid ? fmaxf(m, p) : m;
        float f  = __expf(m - nm);
        float w  = valid ? __expf(p - nm) : 0.f;
        s = s * f + w;
        #pragma unroll
        for (int i = 0; i < 8; ++i) acc[i] = acc[i] * f + w * bf2f((unsigned short)vv[i]);
        m = nm;
    }
    // merge the 8 edge streams (xor 8, 16, 32)
    #pragma unroll
    for (int mask = 8; mask <= 32; mask <<= 1) {
        float om = __shfl_xor(m, mask, 64);
        float os = __shfl_xor(s, mask, 64);
        float oa[8];
        #pragma unroll
        for (int i = 0; i < 8; ++i) oa[i] = __shfl_xor(acc[i], mask, 64);
        float M_ = fmaxf(m, om);
        float f  = __expf(m - M_);
        float of = __expf(om - M_);
        s = s * f + os * of;
        #pragma unroll
        for (int i = 0; i < 8; ++i) acc[i] = acc[i] * f + oa[i] * of;
        m = M_;
    }
    if (g == 0) {
        float inv = 1.f / (s + 1e-16f);
        float4 o0, o1;
        float r[8];
        #pragma unroll
        for (int i = 0; i < 8; ++i)
            r[i] = acc[i] * inv + bf2f(bi[192 + 8 * sl + i]);
        o0 = make_float4(r[0], r[1], r[2], r[3]);
        o1 = make_float4(r[4], r[5], r[6], r[7]);
        float* op = outp + (size_t)wid * 64 + 8 * sl;
        *reinterpret_cast<float4*>(op)     = o0;
        *reinterpret_cast<float4*>(op + 4) = o1;
    }
}

// ---------------- global mean pool (batch is sorted) ----------------
__device__ __forceinline__ int lbound(const int* __restrict__ a, int n, int key) {
    int lo = 0, hi = n;
    while (lo < hi) {
        int mid = (lo + hi) >> 1;
        if (a[mid] < key) lo = mid + 1; else hi = mid;
    }
    return lo;
}

__global__ void pool_mean(const float* __restrict__ h, const int* __restrict__ batch,
                          float* __restrict__ pooled) {
    __shared__ float red[4][64];
    int g = blockIdx.x;
    int l = threadIdx.x & 63;
    int w = threadIdx.x >> 6;
    int lo = lbound(batch, NNODES, g);
    int hi = lbound(batch, NNODES, g + 1);
    float s = 0.f;
    for (int i = lo + w; i < hi; i += 4) s += h[(size_t)i * 64 + l];
    red[w][l] = s;
    __syncthreads();
    if (w == 0) {
        float t = red[0][l] + red[1][l] + red[2][l] + red[3][l];
        float cnt = (float)((hi - lo) > 1 ? (hi - lo) : 1);
        pooled[g * 64 + l] = t / cnt;
    }
}

// ---------------- head MLP ----------------
__global__ void head_mlp(const float* __restrict__ pooled,
                         const float* __restrict__ l1W, const float* __restrict__ l1b,
                         const float* __restrict__ l2W, const float* __restrict__ l2b,
                         float* __restrict__ out) {
    int g = blockIdx.x;
    int l = threadIdx.x & 63;
    float p = pooled[g * 64 + l];
    float hsum = l1b[l];
    #pragma unroll
    for (int kk = 0; kk < 64; ++kk) {
        float pk = __shfl(p, kk, 64);
        hsum += pk * l1W[kk * 64 + l];
    }
    float h = fmaxf(hsum, 0.f);
    float o0 = h * l2W[l * 2 + 0];
    float o1 = h * l2W[l * 2 + 1];
    #pragma unroll
    for (int off = 32; off > 0; off >>= 1) {
        o0 += __shfl_xor(o0, off, 64);
        o1 += __shfl_xor(o1, off, 64);
    }
    if (l == 0) {
        out[g * 2 + 0] = o0 + l2b[0];
        out[g * 2 + 1] = o1 + l2b[1];
    }
}

// ---------------- host launch ----------------
extern "C" void kernel_launch(void* const* d_in, const int* in_sizes, int n_in,
                              void* d_out, int out_size, void* d_ws, size_t ws_size,
                              hipStream_t stream) {
    const float* x      = (const float*)d_in[0];
    const int*   ei     = (const int*)d_in[1];
    const int*   batch  = (const int*)d_in[2];
    const float* syn_W  = (const float*)d_in[3];  const float* syn_b = (const float*)d_in[4];
    const float* ant_W  = (const float*)d_in[5];  const float* ant_b = (const float*)d_in[6];
    const float* fus_W  = (const float*)d_in[7];  const float* fus_b = (const float*)d_in[8];
    const float* c1_Wq  = (const float*)d_in[9];  const float* c1_bq = (const float*)d_in[10];
    const float* c1_Wk  = (const float*)d_in[11]; const float* c1_bk = (const float*)d_in[12];
    const float* c1_Wv  = (const float*)d_in[13]; const float* c1_bv = (const float*)d_in[14];
    const float* c1_Ws  = (const float*)d_in[15]; const float* c1_bs = (const float*)d_in[16];
    const float* c2_Wq  = (const float*)d_in[17]; const float* c2_bq = (const float*)d_in[18];
    const float* c2_Wk  = (const float*)d_in[19]; const float* c2_bk = (const float*)d_in[20];
    const float* c2_Wv  = (const float*)d_in[21]; const float* c2_bv = (const float*)d_in[22];
    const float* c2_Ws  = (const float*)d_in[23]; const float* c2_bs = (const float*)d_in[24];
    const float* l1_W   = (const float*)d_in[25]; const float* l1_b  = (const float*)d_in[26];
    const float* l2_W   = (const float*)d_in[27]; const float* l2_b  = (const float*)d_in[28];
    const int* src = ei;
    const int* dst = ei + NEDGES;
    float* out = (float*)d_out;

    char* ws = (char*)d_ws;
    size_t off = 0;
    auto alloc = [&](size_t bytes) -> char* {
        char* p = ws + off;
        off += (bytes + 255) & ~((size_t)255);
        return p;
    };

    unsigned short* xfin  = (unsigned short*)alloc((size_t)NNODES * 128 * 2);  // enc out; later H (conv1 out)
    unsigned short* xfus  = (unsigned short*)alloc((size_t)NNODES * 128 * 2);  // fused; later H2 (f32 64-wide)
    unsigned short* qkvs1 = (unsigned short*)alloc((size_t)NNODES * 512 * 2);
    unsigned short* qkvs2 = (unsigned short*)alloc((size_t)NNODES * 256 * 2);
    unsigned short* enc_t = (unsigned short*)alloc((size_t)128 * 300 * 2);
    unsigned short* fus_t = (unsigned short*)alloc((size_t)128 * 128 * 2);
    unsigned short* c1w_t = (unsigned short*)alloc((size_t)512 * 128 * 2);
    unsigned short* c2w_t = (unsigned short*)alloc((size_t)256 * 128 * 2);
    float* enc_b = (float*)alloc(128 * 4);
    float* c1_b  = (float*)alloc(512 * 4);
    float* c2_b  = (float*)alloc(256 * 4);
    int*   deg    = (int*)alloc((NNODES + 1) * 4);
    int*   cursor = (int*)alloc((NNODES + 1) * 4);
    int*   rowptr = (int*)alloc((NNODES + 1) * 4);
    int*   bsum   = (int*)alloc(256 * 4);
    int*   esrc   = (int*)alloc((size_t)NEDGES * 4);
    float* pooled = (float*)alloc((size_t)NGRAPH * 64 * 4);

    const int MB = (NNODES + BM - 1) / BM;   // 391
    const int EB = (NEDGES + 255) / 256;
    const int NB = (NNODES + 255) / 256;
    dim3 t256(256);

    // --- weight transposes (slices of fused buffers) ---
    WTArgs wa;
    wa.w[0] = syn_W;  wa.o[0] = enc_t;             wa.K[0] = 300; wa.N[0] = 64;
    wa.w[1] = ant_W;  wa.o[1] = enc_t + 64 * 300;  wa.K[1] = 300; wa.N[1] = 64;
    wa.w[2] = fus_W;  wa.o[2] = fus_t;             wa.K[2] = 128; wa.N[2] = 128;
    wa.w[3] = c1_Wq;  wa.o[3] = c1w_t + 0 * 128 * 128; wa.K[3] = 128; wa.N[3] = 128;
    wa.w[4] = c1_Wk;  wa.o[4] = c1w_t + 1 * 128 * 128; wa.K[4] = 128; wa.N[4] = 128;
    wa.w[5] = c1_Wv;  wa.o[5] = c1w_t + 2 * 128 * 128; wa.K[5] = 128; wa.N[5] = 128;
    wa.w[6] = c1_Ws;  wa.o[6] = c1w_t + 3 * 128 * 128; wa.K[6] = 128; wa.N[6] = 128;
    wa.w[7] = c2_Wq;  wa.o[7] = c2w_t + 0 * 64 * 128;  wa.K[7] = 128; wa.N[7] = 64;
    wa.w[8] = c2_Wk;  wa.o[8] = c2w_t + 1 * 64 * 128;  wa.K[8] = 128; wa.N[8] = 64;
    wa.w[9] = c2_Wv;  wa.o[9] = c2w_t + 2 * 64 * 128;  wa.K[9] = 128; wa.N[9] = 64;
    wa.w[10] = c2_Ws; wa.o[10] = c2w_t + 3 * 64 * 128; wa.K[10] = 128; wa.N[10] = 64;
    k_wt<<<dim3(75, 11), t256, 0, stream>>>(wa);

    BiasArgs ba;
    ba.syn_b = syn_b; ba.ant_b = ant_b;
    ba.c1q = c1_bq; ba.c1k = c1_bk; ba.c1v = c1_bv; ba.c1s = c1_bs;
    ba.c2q = c2_bq; ba.c2k = c2_bk; ba.c2v = c2_bv; ba.c2s = c2_bs;
    ba.enc_b = enc_b; ba.c1_b = c1_b; ba.c2_b = c2_b;
    k_bias<<<1, 1024, 0, stream>>>(ba);

    // --- CSR build ---
    hipMemsetAsync(deg, 0, (NNODES + 1) * sizeof(int), stream);
    k_hist<<<EB, t256, 0, stream>>>(dst, deg, NEDGES);
    k_scan1<<<NB, t256, 0, stream>>>(deg, rowptr, bsum, NNODES);
    k_scan2<<<1, t256, 0, stream>>>(bsum, NB);
    k_scan3<<<NB, t256, 0, stream>>>(rowptr, bsum, cursor, NNODES, NEDGES);
    k_fill<<<EB, t256, 0, stream>>>(src, dst, cursor, esrc, NEDGES);

    // --- encoders (fused syn||ant) + relu ---
    gemm_mfma<false><<<dim3(MB, 2), t256, 0, stream>>>(x, INC, NNODES, INC, enc_t, enc_b, xfin, 128, 1);
    // --- fusion ---
    gemm_mfma<true><<<dim3(MB, 2), t256, 0, stream>>>(xfin, 128, NNODES, 128, fus_t, fus_b, xfus, 128, 0);
    // --- conv1 q|k|v|s fused (N=512) ---
    gemm_mfma<true><<<dim3(MB, 8), t256, 0, stream>>>(xfus, 128, NNODES, 128, c1w_t, c1_b, qkvs1, 512, 0);
    // --- conv1 attention + relu -> H ---
    unsigned short* H = xfin;
    attn_h2<<<(NNODES * 64 + 255) / 256, t256, 0, stream>>>(qkvs1, rowptr, esrc, H, NNODES);
    // --- conv2 q|k|v|s fused (N=256) ---
    gemm_mfma<true><<<dim3(MB, 4), t256, 0, stream>>>(H, 128, NNODES, 128, c2w_t, c2_b, qkvs2, 256, 0);
    // --- conv2 attention -> H2 (f32) ---
    float* H2 = (float*)xfus;
    attn_h1<<<(NNODES * 64 + 255) / 256, t256, 0, stream>>>(qkvs2, rowptr, esrc, H2, NNODES);

    // --- pool + head ---
    pool_mean<<<NGRAPH, 256, 0, stream>>>(H2, batch, pooled);
    head_mlp<<<NGRAPH, 64, 0, stream>>>(pooled, l1_W, l1_b, l2_W, l2_b, out);
}